// Round 2
// baseline (825.551 us; speedup 1.0000x reference)
//
#include <hip/hip_runtime.h>

// out[i] = l1 * prod_{e: idx[e]==i} factor[e]
// log(factor) = logC - 0.5 z^2, logC = log(t0c * INV_SQRT_2PI / t1)
// Accumulate logs with f32 atomicAdd into d_out, then exponentiate.
//
// R2 change: batch 16 events per thread (vectorized loads, then 16
// back-to-back fire-and-forget atomics, then exit) so the in-order vmcnt
// queue never forces a wait on atomic completion -> maximize in-flight
// memory-side RMWs.

#define INV_SQRT_2PI 0.39894246f  // 1/sqrt(2*3.14159) (matches reference)

__global__ void init_zero_kernel(float* __restrict__ out, int n) {
    int i = blockIdx.x * blockDim.x + threadIdx.x;
    int stride = gridDim.x * blockDim.x;
    for (; i < n; i += stride) out[i] = 0.0f;
}

__global__ __launch_bounds__(256) void scatter_log_kernel(
        const int* __restrict__ idx,
        const float* __restrict__ vals,
        const float* __restrict__ thetas,
        float* __restrict__ acc, int n) {
    float t0 = thetas[0], t1 = thetas[1], t2 = thetas[2];
    float t0c = fminf(fmaxf(t0, 0.0f), 1.0f);
    float logC = logf(t0c * INV_SQRT_2PI / t1);
    float inv_t1 = 1.0f / t1;

    long long t = (long long)blockIdx.x * blockDim.x + threadIdx.x;
    long long base = t * 16;
    if (base >= n) return;

    if (base + 16 <= n) {
        // fast path: 4x int4 + 4x float4 loads, 16 atomics
        int4 i0 = *(const int4*)(idx + base);
        int4 i1 = *(const int4*)(idx + base + 4);
        int4 i2 = *(const int4*)(idx + base + 8);
        int4 i3 = *(const int4*)(idx + base + 12);
        float4 v0 = *(const float4*)(vals + base);
        float4 v1 = *(const float4*)(vals + base + 4);
        float4 v2 = *(const float4*)(vals + base + 8);
        float4 v3 = *(const float4*)(vals + base + 12);

        int   ki[16] = {i0.x,i0.y,i0.z,i0.w, i1.x,i1.y,i1.z,i1.w,
                        i2.x,i2.y,i2.z,i2.w, i3.x,i3.y,i3.z,i3.w};
        float vv[16] = {v0.x,v0.y,v0.z,v0.w, v1.x,v1.y,v1.z,v1.w,
                        v2.x,v2.y,v2.z,v2.w, v3.x,v3.y,v3.z,v3.w};

        float lf[16];
        #pragma unroll
        for (int j = 0; j < 16; ++j) {
            float z = (vv[j] - t2) * inv_t1;
            lf[j] = fmaf(-0.5f * z, z, logC);
        }
        #pragma unroll
        for (int j = 0; j < 16; ++j) {
            atomicAdd(&acc[ki[j]], lf[j]);
        }
    } else {
        for (long long e = base; e < n; ++e) {
            float z = (vals[e] - t2) * inv_t1;
            atomicAdd(&acc[idx[e]], fmaf(-0.5f * z, z, logC));
        }
    }
}

__global__ void finalize_kernel(float* __restrict__ out,
                                const float* __restrict__ thetas, int n) {
    float t0c = fminf(fmaxf(thetas[0], 0.0f), 1.0f);
    float cond = 1.0f - t0c;
    int i = blockIdx.x * blockDim.x + threadIdx.x;
    int stride = gridDim.x * blockDim.x;
    for (; i < n; i += stride) out[i] = cond * expf(out[i]);
}

extern "C" void kernel_launch(void* const* d_in, const int* in_sizes, int n_in,
                              void* d_out, int out_size, void* d_ws, size_t ws_size,
                              hipStream_t stream) {
    // inputs: [0]=batch (scalar), [1]=idx (int32), [2]=vals (f32), [3]=thetas (f32 x3)
    const int*   idx    = (const int*)d_in[1];
    const float* vals   = (const float*)d_in[2];
    const float* thetas = (const float*)d_in[3];
    float*       out    = (float*)d_out;

    int n_events = in_sizes[1];
    int n_out    = out_size;

    const int BLOCK = 256;
    int grid_out = min((n_out + BLOCK - 1) / BLOCK, 2048);

    // one thread per 16 events
    long long n_threads = (n_events + 15) / 16;
    int grid_ev = (int)((n_threads + BLOCK - 1) / BLOCK);

    init_zero_kernel<<<grid_out, BLOCK, 0, stream>>>(out, n_out);
    scatter_log_kernel<<<grid_ev, BLOCK, 0, stream>>>(idx, vals, thetas, out, n_events);
    finalize_kernel<<<grid_out, BLOCK, 0, stream>>>(out, thetas, n_out);
}

// Round 3
// 436.669 us; speedup vs baseline: 1.8906x; 1.8906x over previous
//
#include <hip/hip_runtime.h>

// out[i] = l1 * prod_{e: idx[e]==i} factor[e]
// log(factor) = logC - 0.5 z^2, logC = log(t0c * INV_SQRT_2PI / t1)
//
// R3: global-atomic-free. Phase 1 bins events into 512 buckets of 16384
// output slots (counting-sort with per-block LDS histograms; ~0.5M global
// atomics instead of 16.7M). Phase 2: one block per bucket accumulates
// log-factors in a 64KB LDS array via LDS atomics, then writes
// cond*exp(acc) directly (init+finalize fused away).

#define INV_SQRT_2PI 0.39894246f  // 1/sqrt(2*3.14159) (matches reference)
#define SLOT_BITS 14
#define SLOTS (1 << SLOT_BITS)
#define MAXB 1024

__global__ void zero_ints_kernel(int* __restrict__ p, int n) {
    int i = blockIdx.x * blockDim.x + threadIdx.x;
    if (i < n) p[i] = 0;
}

__global__ __launch_bounds__(256) void binning_kernel(
        const int* __restrict__ idx,
        const float* __restrict__ vals,
        const float* __restrict__ thetas,
        uint2* __restrict__ pairs,   // [nbuckets][cap]
        int* __restrict__ fill,      // [nbuckets]
        int n, int cap, int nbuckets, int epb) {
    __shared__ int hist[MAXB];      // counts, then cursors
    const int tid = threadIdx.x;

    long long start = (long long)blockIdx.x * epb;
    long long end   = start + epb;
    if (end > n) end = n;
    if (start >= end) return;

    for (int b = tid; b < nbuckets; b += blockDim.x) hist[b] = 0;
    __syncthreads();

    long long vecEnd = start + ((end - start) & ~3LL);

    // pass A: count
    for (long long e = start + (long long)tid * 4; e < vecEnd; e += (long long)blockDim.x * 4) {
        int4 k = *(const int4*)(idx + e);
        atomicAdd(&hist[(unsigned)k.x >> SLOT_BITS], 1);
        atomicAdd(&hist[(unsigned)k.y >> SLOT_BITS], 1);
        atomicAdd(&hist[(unsigned)k.z >> SLOT_BITS], 1);
        atomicAdd(&hist[(unsigned)k.w >> SLOT_BITS], 1);
    }
    {
        long long e = vecEnd + tid;
        if (e < end) atomicAdd(&hist[(unsigned)idx[e] >> SLOT_BITS], 1);
    }
    __syncthreads();

    // reserve space per bucket (one global atomic per block-bucket with events)
    for (int b = tid; b < nbuckets; b += blockDim.x) {
        int c = hist[b];
        hist[b] = (c > 0) ? atomicAdd(&fill[b], c) : 0;  // hist becomes cursor
    }
    __syncthreads();

    float t1 = thetas[1], t2 = thetas[2];
    float t0c = fminf(fmaxf(thetas[0], 0.0f), 1.0f);
    float logC = logf(t0c * INV_SQRT_2PI / t1);
    float inv_t1 = 1.0f / t1;

    // pass B: scatter (local_slot, log_factor) into bucket regions
    for (long long e = start + (long long)tid * 4; e < vecEnd; e += (long long)blockDim.x * 4) {
        int4   k = *(const int4*)(idx + e);
        float4 v = *(const float4*)(vals + e);
        int   ks[4] = {k.x, k.y, k.z, k.w};
        float vs[4] = {v.x, v.y, v.z, v.w};
        #pragma unroll
        for (int j = 0; j < 4; ++j) {
            int b = (unsigned)ks[j] >> SLOT_BITS;
            float z = (vs[j] - t2) * inv_t1;
            float lf = fmaf(-0.5f * z, z, logC);
            int pos = atomicAdd(&hist[b], 1);
            if (pos < cap)
                pairs[(long long)b * cap + pos] =
                    make_uint2((unsigned)ks[j] & (SLOTS - 1), __float_as_uint(lf));
        }
    }
    {
        long long e = vecEnd + tid;
        if (e < end) {
            int kk = idx[e];
            int b = (unsigned)kk >> SLOT_BITS;
            float z = (vals[e] - t2) * inv_t1;
            float lf = fmaf(-0.5f * z, z, logC);
            int pos = atomicAdd(&hist[b], 1);
            if (pos < cap)
                pairs[(long long)b * cap + pos] =
                    make_uint2((unsigned)kk & (SLOTS - 1), __float_as_uint(lf));
        }
    }
}

__global__ __launch_bounds__(256) void reduce_kernel(
        const uint2* __restrict__ pairs,
        const int* __restrict__ fill,
        const float* __restrict__ thetas,
        float* __restrict__ out, long long n_out, int cap) {
    __shared__ float acc[SLOTS];    // 64 KB
    const int tid = threadIdx.x;
    const int b = blockIdx.x;

    for (int s = tid; s < SLOTS; s += blockDim.x) acc[s] = 0.0f;
    __syncthreads();

    int nb = fill[b];
    if (nb > cap) nb = cap;
    const uint2* p = pairs + (long long)b * cap;
    for (int i = tid; i < nb; i += blockDim.x) {
        uint2 pr = p[i];
        atomicAdd(&acc[pr.x], __uint_as_float(pr.y));
    }
    __syncthreads();

    float t0c = fminf(fmaxf(thetas[0], 0.0f), 1.0f);
    float cond = 1.0f - t0c;
    long long obase = (long long)b << SLOT_BITS;
    for (int s = tid; s < SLOTS; s += blockDim.x) {
        long long o = obase + s;
        if (o < n_out) out[o] = cond * expf(acc[s]);
    }
}

// ---- fallback path (R1): direct global atomics, used if ws too small ----
__global__ void init_zero_kernel(float* __restrict__ out, int n) {
    int i = blockIdx.x * blockDim.x + threadIdx.x;
    int stride = gridDim.x * blockDim.x;
    for (; i < n; i += stride) out[i] = 0.0f;
}
__global__ void scatter_log_kernel(const int* __restrict__ idx,
                                   const float* __restrict__ vals,
                                   const float* __restrict__ thetas,
                                   float* __restrict__ acc, int n) {
    float t1 = thetas[1], t2 = thetas[2];
    float t0c = fminf(fmaxf(thetas[0], 0.0f), 1.0f);
    float logC = logf(t0c * INV_SQRT_2PI / t1);
    float inv_t1 = 1.0f / t1;
    int i = blockIdx.x * blockDim.x + threadIdx.x;
    int stride = gridDim.x * blockDim.x;
    for (; i < n; i += stride) {
        float z = (vals[i] - t2) * inv_t1;
        atomicAdd(&acc[idx[i]], fmaf(-0.5f * z, z, logC));
    }
}
__global__ void finalize_kernel(float* __restrict__ out,
                                const float* __restrict__ thetas, int n) {
    float t0c = fminf(fmaxf(thetas[0], 0.0f), 1.0f);
    float cond = 1.0f - t0c;
    int i = blockIdx.x * blockDim.x + threadIdx.x;
    int stride = gridDim.x * blockDim.x;
    for (; i < n; i += stride) out[i] = cond * expf(out[i]);
}

extern "C" void kernel_launch(void* const* d_in, const int* in_sizes, int n_in,
                              void* d_out, int out_size, void* d_ws, size_t ws_size,
                              hipStream_t stream) {
    // inputs: [0]=batch (scalar), [1]=idx (int32), [2]=vals (f32), [3]=thetas (f32 x3)
    const int*   idx    = (const int*)d_in[1];
    const float* vals   = (const float*)d_in[2];
    const float* thetas = (const float*)d_in[3];
    float*       out    = (float*)d_out;

    int n_events = in_sizes[1];
    long long n_out = out_size;

    int nbuckets = (int)((n_out + SLOTS - 1) >> SLOT_BITS);

    // capacity per bucket: avg + margin (sigma ~ sqrt(avg); margin >> 6 sigma)
    long long avg = (n_events + nbuckets - 1) / nbuckets;
    long long cap = avg + avg / 16 + 1024;
    size_t pairs_off = 4096;
    size_t needed = pairs_off + (size_t)nbuckets * (size_t)cap * sizeof(uint2);

    if (nbuckets <= MAXB && ws_size >= needed && n_events > 0) {
        int* fill = (int*)d_ws;
        uint2* pairs = (uint2*)((char*)d_ws + pairs_off);

        const int BLOCK = 256;
        // phase 1 grid: ~1024 blocks, events_per_block multiple of 1024
        int nb1 = 1024;
        long long epb_ll = ((n_events + nb1 - 1) / nb1 + 1023) & ~1023LL;
        int epb = (int)epb_ll;
        int grid1 = (int)((n_events + epb - 1) / epb);

        zero_ints_kernel<<<(nbuckets + 255) / 256, 256, 0, stream>>>(fill, nbuckets);
        binning_kernel<<<grid1, BLOCK, 0, stream>>>(idx, vals, thetas, pairs, fill,
                                                    n_events, (int)cap, nbuckets, epb);
        reduce_kernel<<<nbuckets, BLOCK, 0, stream>>>(pairs, fill, thetas, out,
                                                      n_out, (int)cap);
    } else {
        const int BLOCK = 256;
        int grid_out = min((int)((n_out + BLOCK - 1) / BLOCK), 2048);
        int grid_ev  = min((n_events + BLOCK - 1) / BLOCK, 2048);
        init_zero_kernel<<<grid_out, BLOCK, 0, stream>>>(out, (int)n_out);
        scatter_log_kernel<<<grid_ev, BLOCK, 0, stream>>>(idx, vals, thetas, out, n_events);
        finalize_kernel<<<grid_out, BLOCK, 0, stream>>>(out, thetas, (int)n_out);
    }
}

// Round 4
// 199.312 us; speedup vs baseline: 4.1420x; 2.1909x over previous
//
#include <hip/hip_runtime.h>

// out[i] = cond * prod_{e: idx[e]==i} factor[e];  cond = 1 - clip(t0,0,1)
// log(factor) = logC - u,  u = 0.5*((v-t2)/t1)^2,  logC = log(t0c*INV_SQRT_2PI/t1)
//
// R4: binning with block-private output regions (no global reservation
// atomics), 4-byte packed records (slot:14 | q:18, q = rint(u*8192)),
// LDS staging flushed in 64B-aligned 16-record chunks -> no partial-line
// write amplification. Reduce: one block per 16384-slot bucket, LDS f32
// accumulate, fused cond*exp write.

#define INV_SQRT_2PI 0.39894246f  // 1/sqrt(2*3.14159) (matches reference)
#define SLOT_BITS 14
#define SLOTS (1 << SLOT_BITS)
#define NB_MAX 512          // max buckets for fast path
#define NBLK 512            // binning blocks (block-private regions)
#define TILE 2048           // events per block-tile (8 per thread)
#define STAGE_S 28          // stage depth per bucket (records)
#define QSCALE 8192.0f
#define QMASK 0x3FFFFu      // 18 bits

__global__ void zero_ovf_kernel(int* p) { *p = 0; }

__device__ __forceinline__ void ovf_push(uint2* ovf, int* ovf_cnt, int ovcap,
                                         unsigned gslot, float lf) {
    int op = atomicAdd(ovf_cnt, 1);
    if (op < ovcap) ovf[op] = make_uint2(gslot, __float_as_uint(lf));
}

__global__ __launch_bounds__(256) void bin_kernel(
        const int* __restrict__ idx, const float* __restrict__ vals,
        const float* __restrict__ thetas,
        unsigned* __restrict__ pairs,  // [NBLK][nbuckets][cappb]
        int* __restrict__ fill,        // [NBLK][nbuckets] valid counts
        uint2* __restrict__ ovf, int* __restrict__ ovf_cnt, int ovcap,
        int n, int nbuckets, int cappb, int epb) {
    __shared__ unsigned stage[NB_MAX * STAGE_S];  // 56 KB
    __shared__ int scnt[NB_MAX];
    __shared__ int cnum[NB_MAX];                  // 64B chunks written

    const int tid = threadIdx.x;
    const int blk = blockIdx.x;
    long long start = (long long)blk * epb;
    long long end = start + epb;
    if (end > n) end = n;

    for (int b = tid; b < nbuckets; b += 256) { scnt[b] = 0; cnum[b] = 0; }
    __syncthreads();

    const float t1 = thetas[1], t2 = thetas[2];
    const float t0c = fminf(fmaxf(thetas[0], 0.0f), 1.0f);
    const float logC = logf(t0c * INV_SQRT_2PI / t1);
    const float inv_t1 = 1.0f / t1;

    for (long long ts = start; ts < end; ts += TILE) {
        long long te = ts + TILE; if (te > end) te = end;
        long long base = ts + (long long)tid * 8;

        // ---- scatter 8 events into LDS stage ----
        int   ks[8]; float vs[8]; int cnt_ev = 0;
        if (base + 8 <= te) {
            int4 k0 = *(const int4*)(idx + base);
            int4 k1 = *(const int4*)(idx + base + 4);
            float4 v0 = *(const float4*)(vals + base);
            float4 v1 = *(const float4*)(vals + base + 4);
            ks[0]=k0.x;ks[1]=k0.y;ks[2]=k0.z;ks[3]=k0.w;
            ks[4]=k1.x;ks[5]=k1.y;ks[6]=k1.z;ks[7]=k1.w;
            vs[0]=v0.x;vs[1]=v0.y;vs[2]=v0.z;vs[3]=v0.w;
            vs[4]=v1.x;vs[5]=v1.y;vs[6]=v1.z;vs[7]=v1.w;
            cnt_ev = 8;
        } else {
            for (long long e = base; e < te; ++e) {
                ks[cnt_ev] = idx[e]; vs[cnt_ev] = vals[e]; ++cnt_ev;
            }
        }
        for (int j = 0; j < cnt_ev; ++j) {
            unsigned uk = (unsigned)ks[j];
            int b = uk >> SLOT_BITS;
            if (b >= nbuckets) continue;
            float z = (vs[j] - t2) * inv_t1;
            float u = 0.5f * z * z;
            unsigned q = __float2uint_rn(fminf(u * QSCALE, (float)QMASK));
            unsigned rec = ((uk & (SLOTS - 1)) << 18) | q;
            int pos = atomicAdd(&scnt[b], 1);
            if (pos < STAGE_S) stage[b * STAGE_S + pos] = rec;
            else ovf_push(ovf, ovf_cnt, ovcap, uk, logC - u);
        }
        __syncthreads();

        // ---- flush full 64B chunks ----
        for (int b = tid; b < nbuckets; b += 256) {
            int c = scnt[b]; if (c > STAGE_S) c = STAGE_S;
            if (c >= 16) {
                int have = cnum[b];
                if (have < (cappb >> 4)) {
                    unsigned* dst = pairs +
                        (((long long)blk * nbuckets + b) * cappb + (have << 4));
                    const uint4* s4 = (const uint4*)&stage[b * STAGE_S];
                    uint4* d4 = (uint4*)dst;
                    d4[0]=s4[0]; d4[1]=s4[1]; d4[2]=s4[2]; d4[3]=s4[3];
                    cnum[b] = have + 1;
                    int rem = c - 16;
                    for (int i = 0; i < rem; ++i)
                        stage[b*STAGE_S + i] = stage[b*STAGE_S + 16 + i];
                    scnt[b] = rem;
                } else {  // region full (shouldn't happen): spill all to ovf
                    for (int i = 0; i < c; ++i) {
                        unsigned r = stage[b*STAGE_S + i];
                        ovf_push(ovf, ovf_cnt, ovcap,
                                 ((unsigned)b << SLOT_BITS) | (r >> 18),
                                 logC - (float)(r & QMASK) * (1.0f/QSCALE));
                    }
                    scnt[b] = 0;
                }
            } else scnt[b] = c;
        }
        __syncthreads();
    }

    // ---- final flush: write remainder (64B-padded), record valid counts ----
    for (int b = tid; b < nbuckets; b += 256) {
        int c = scnt[b]; if (c > STAGE_S) c = STAGE_S;
        int have = cnum[b];
        int valid = have << 4;
        int nfull = (c + 15) >> 4;              // 0..2 chunks
        int fit = (cappb >> 4) - have;
        int nw = nfull < fit ? nfull : fit;
        if (nw > 0) {
            unsigned* dst = pairs +
                (((long long)blk * nbuckets + b) * cappb + (have << 4));
            const uint4* s4 = (const uint4*)&stage[b * STAGE_S];
            uint4* d4 = (uint4*)dst;
            for (int ch = 0; ch < nw; ++ch) {
                d4[ch*4+0]=s4[ch*4+0]; d4[ch*4+1]=s4[ch*4+1];
                d4[ch*4+2]=s4[ch*4+2]; d4[ch*4+3]=s4[ch*4+3];
            }
            int v2 = nw << 4; if (v2 > c) v2 = c;
            valid += v2;
        }
        for (int i = (nw << 4); i < c; ++i) {   // unfit tail -> ovf (rare)
            unsigned r = stage[b*STAGE_S + i];
            ovf_push(ovf, ovf_cnt, ovcap,
                     ((unsigned)b << SLOT_BITS) | (r >> 18),
                     logC - (float)(r & QMASK) * (1.0f/QSCALE));
        }
        fill[blk * nbuckets + b] = valid;
    }
}

__global__ __launch_bounds__(256) void reduce_kernel(
        const unsigned* __restrict__ pairs, const int* __restrict__ fill,
        const uint2* __restrict__ ovf, const int* __restrict__ ovf_cnt, int ovcap,
        const float* __restrict__ thetas, float* __restrict__ out,
        long long n_out, int nbuckets, int cappb) {
    __shared__ float acc[SLOTS];  // 64 KB
    const int tid = threadIdx.x;
    const int b = blockIdx.x;

    for (int s = tid; s < SLOTS; s += 256) acc[s] = 0.0f;
    __syncthreads();

    const float t1 = thetas[1];
    const float t0c = fminf(fmaxf(thetas[0], 0.0f), 1.0f);
    const float logC = logf(t0c * INV_SQRT_2PI / t1);

    const int wave = tid >> 6, lane = tid & 63;
    for (int blk = wave; blk < NBLK; blk += 4) {
        int cnt = fill[blk * nbuckets + b];
        const unsigned* p = pairs + ((long long)blk * nbuckets + b) * cappb;
        for (int i = lane; i < cnt; i += 64) {
            unsigned r = p[i];
            atomicAdd(&acc[r >> 18],
                      logC - (float)(r & QMASK) * (1.0f/QSCALE));
        }
    }
    __syncthreads();

    int no = *ovf_cnt; if (no > ovcap) no = ovcap;
    for (int i = tid; i < no; i += 256) {
        uint2 e = ovf[i];
        if ((int)(e.x >> SLOT_BITS) == b)
            atomicAdd(&acc[e.x & (SLOTS - 1)], __uint_as_float(e.y));
    }
    __syncthreads();

    const float cond = 1.0f - t0c;
    long long obase = (long long)b << SLOT_BITS;
    for (int s = tid; s < SLOTS; s += 256) {
        long long o = obase + s;
        if (o < n_out) out[o] = cond * expf(acc[s]);
    }
}

// ---- fallback path: direct global atomics (R1) ----
__global__ void init_zero_kernel(float* __restrict__ out, int n) {
    int i = blockIdx.x * blockDim.x + threadIdx.x;
    int stride = gridDim.x * blockDim.x;
    for (; i < n; i += stride) out[i] = 0.0f;
}
__global__ void scatter_log_kernel(const int* __restrict__ idx,
                                   const float* __restrict__ vals,
                                   const float* __restrict__ thetas,
                                   float* __restrict__ acc, int n) {
    float t1 = thetas[1], t2 = thetas[2];
    float t0c = fminf(fmaxf(thetas[0], 0.0f), 1.0f);
    float logC = logf(t0c * INV_SQRT_2PI / t1);
    float inv_t1 = 1.0f / t1;
    int i = blockIdx.x * blockDim.x + threadIdx.x;
    int stride = gridDim.x * blockDim.x;
    for (; i < n; i += stride) {
        float z = (vals[i] - t2) * inv_t1;
        atomicAdd(&acc[idx[i]], fmaf(-0.5f * z, z, logC));
    }
}
__global__ void finalize_kernel(float* __restrict__ out,
                                const float* __restrict__ thetas, int n) {
    float t0c = fminf(fmaxf(thetas[0], 0.0f), 1.0f);
    float cond = 1.0f - t0c;
    int i = blockIdx.x * blockDim.x + threadIdx.x;
    int stride = gridDim.x * blockDim.x;
    for (; i < n; i += stride) out[i] = cond * expf(out[i]);
}

extern "C" void kernel_launch(void* const* d_in, const int* in_sizes, int n_in,
                              void* d_out, int out_size, void* d_ws, size_t ws_size,
                              hipStream_t stream) {
    // inputs: [0]=batch (scalar), [1]=idx (int32), [2]=vals (f32), [3]=thetas (f32 x3)
    const int*   idx    = (const int*)d_in[1];
    const float* vals   = (const float*)d_in[2];
    const float* thetas = (const float*)d_in[3];
    float*       out    = (float*)d_out;

    int n_events = in_sizes[1];
    long long n_out = out_size;
    int nbuckets = (int)((n_out + SLOTS - 1) >> SLOT_BITS);

    // geometry
    long long tiles_total = ((long long)n_events + TILE - 1) / TILE;
    long long tpb = (tiles_total + NBLK - 1) / NBLK;
    int epb = (int)(tpb * TILE);
    long long avg = nbuckets > 0 ? (epb + nbuckets - 1) / nbuckets : 0;
    int cappb = (int)((avg + avg / 2 + 32 + 15) & ~15LL);

    size_t pairs_b = (size_t)NBLK * nbuckets * cappb * 4;
    size_t fill_b  = (size_t)NBLK * nbuckets * 4;
    size_t head    = pairs_b + fill_b + 64;
    bool fast = (nbuckets > 0) && (nbuckets <= NB_MAX) && (n_events > 0) &&
                (ws_size >= head + 64 * 1024);

    if (fast) {
        unsigned* pairs = (unsigned*)d_ws;
        int* fill = (int*)((char*)d_ws + pairs_b);
        int* ovf_cnt = (int*)((char*)d_ws + pairs_b + fill_b);
        uint2* ovf = (uint2*)((char*)d_ws + head);
        long long ovcap_ll = (long long)((ws_size - head) / 8);
        int ovcap = (int)(ovcap_ll > 4194304 ? 4194304 : ovcap_ll);

        zero_ovf_kernel<<<1, 1, 0, stream>>>(ovf_cnt);
        bin_kernel<<<NBLK, 256, 0, stream>>>(idx, vals, thetas, pairs, fill,
                                             ovf, ovf_cnt, ovcap,
                                             n_events, nbuckets, cappb, epb);
        reduce_kernel<<<nbuckets, 256, 0, stream>>>(pairs, fill, ovf, ovf_cnt,
                                                    ovcap, thetas, out,
                                                    n_out, nbuckets, cappb);
    } else {
        const int BLOCK = 256;
        int grid_out = min((int)((n_out + BLOCK - 1) / BLOCK), 2048);
        int grid_ev  = min((n_events + BLOCK - 1) / BLOCK, 2048);
        init_zero_kernel<<<grid_out, BLOCK, 0, stream>>>(out, (int)n_out);
        scatter_log_kernel<<<grid_ev, BLOCK, 0, stream>>>(idx, vals, thetas, out, n_events);
        finalize_kernel<<<grid_out, BLOCK, 0, stream>>>(out, thetas, (int)n_out);
    }
}

// Round 5
// 189.338 us; speedup vs baseline: 4.3602x; 1.0527x over previous
//
#include <hip/hip_runtime.h>

// out[i] = cond * prod_{e: idx[e]==i} factor[e];  cond = 1 - clip(t0,0,1)
// log(factor) = logC - u,  u = 0.5*((v-t2)/t1)^2,  logC = log(t0c*INV_SQRT_2PI/t1)
//
// R5: pairs layout [bucket][blk][cappb] (cappb = pow2) so reduce streams one
// contiguous span per bucket with coalesced uint4 loads; validity via
// preloaded per-segment counts in LDS (no fill-dependent addressing, no
// serial latency chains). Reduce at 512 threads. Binning unchanged except
// flush addressing.

#define INV_SQRT_2PI 0.39894246f  // 1/sqrt(2*3.14159) (matches reference)
#define SLOT_BITS 14
#define SLOTS (1 << SLOT_BITS)
#define NB_MAX 512          // max buckets for fast path
#define NBLK 512            // binning blocks (block-private regions)
#define TILE 2048           // events per block-tile (8 per thread)
#define STAGE_S 28          // stage depth per bucket (records)
#define QSCALE 8192.0f
#define QMASK 0x3FFFFu      // 18 bits

__global__ void zero_ovf_kernel(int* p) { *p = 0; }

__device__ __forceinline__ void ovf_push(uint2* ovf, int* ovf_cnt, int ovcap,
                                         unsigned gslot, float lf) {
    int op = atomicAdd(ovf_cnt, 1);
    if (op < ovcap) ovf[op] = make_uint2(gslot, __float_as_uint(lf));
}

__global__ __launch_bounds__(256) void bin_kernel(
        const int* __restrict__ idx, const float* __restrict__ vals,
        const float* __restrict__ thetas,
        unsigned* __restrict__ pairs,  // [nbuckets][NBLK][cappb]
        int* __restrict__ fill,        // [nbuckets][NBLK] valid counts
        uint2* __restrict__ ovf, int* __restrict__ ovf_cnt, int ovcap,
        int n, int nbuckets, int cap_shift, int epb) {
    __shared__ unsigned stage[NB_MAX * STAGE_S];  // 56 KB
    __shared__ int scnt[NB_MAX];
    __shared__ int cnum[NB_MAX];                  // 64B chunks written

    const int tid = threadIdx.x;
    const int blk = blockIdx.x;
    const int cappb = 1 << cap_shift;
    long long start = (long long)blk * epb;
    long long end = start + epb;
    if (end > n) end = n;

    for (int b = tid; b < nbuckets; b += 256) { scnt[b] = 0; cnum[b] = 0; }
    __syncthreads();

    const float t1 = thetas[1], t2 = thetas[2];
    const float t0c = fminf(fmaxf(thetas[0], 0.0f), 1.0f);
    const float logC = logf(t0c * INV_SQRT_2PI / t1);
    const float inv_t1 = 1.0f / t1;

    for (long long ts = start; ts < end; ts += TILE) {
        long long te = ts + TILE; if (te > end) te = end;
        long long base = ts + (long long)tid * 8;

        // ---- scatter 8 events into LDS stage ----
        int   ks[8]; float vs[8]; int cnt_ev = 0;
        if (base + 8 <= te) {
            int4 k0 = *(const int4*)(idx + base);
            int4 k1 = *(const int4*)(idx + base + 4);
            float4 v0 = *(const float4*)(vals + base);
            float4 v1 = *(const float4*)(vals + base + 4);
            ks[0]=k0.x;ks[1]=k0.y;ks[2]=k0.z;ks[3]=k0.w;
            ks[4]=k1.x;ks[5]=k1.y;ks[6]=k1.z;ks[7]=k1.w;
            vs[0]=v0.x;vs[1]=v0.y;vs[2]=v0.z;vs[3]=v0.w;
            vs[4]=v1.x;vs[5]=v1.y;vs[6]=v1.z;vs[7]=v1.w;
            cnt_ev = 8;
        } else if (base < te) {
            for (long long e = base; e < te; ++e) {
                ks[cnt_ev] = idx[e]; vs[cnt_ev] = vals[e]; ++cnt_ev;
            }
        }
        for (int j = 0; j < cnt_ev; ++j) {
            unsigned uk = (unsigned)ks[j];
            int b = uk >> SLOT_BITS;
            if (b >= nbuckets) continue;
            float z = (vs[j] - t2) * inv_t1;
            float u = 0.5f * z * z;
            unsigned q = __float2uint_rn(fminf(u * QSCALE, (float)QMASK));
            unsigned rec = ((uk & (SLOTS - 1)) << 18) | q;
            int pos = atomicAdd(&scnt[b], 1);
            if (pos < STAGE_S) stage[b * STAGE_S + pos] = rec;
            else ovf_push(ovf, ovf_cnt, ovcap, uk, logC - u);
        }
        __syncthreads();

        // ---- flush full 64B chunks ----
        for (int b = tid; b < nbuckets; b += 256) {
            int c = scnt[b]; if (c > STAGE_S) c = STAGE_S;
            if (c >= 16) {
                int have = cnum[b];
                if (have < (cappb >> 4)) {
                    unsigned* dst = pairs +
                        (((long long)b * NBLK + blk) << cap_shift) + (have << 4);
                    const uint4* s4 = (const uint4*)&stage[b * STAGE_S];
                    uint4* d4 = (uint4*)dst;
                    d4[0]=s4[0]; d4[1]=s4[1]; d4[2]=s4[2]; d4[3]=s4[3];
                    cnum[b] = have + 1;
                    int rem = c - 16;
                    for (int i = 0; i < rem; ++i)
                        stage[b*STAGE_S + i] = stage[b*STAGE_S + 16 + i];
                    scnt[b] = rem;
                } else {  // region full (shouldn't happen): spill all to ovf
                    for (int i = 0; i < c; ++i) {
                        unsigned r = stage[b*STAGE_S + i];
                        ovf_push(ovf, ovf_cnt, ovcap,
                                 ((unsigned)b << SLOT_BITS) | (r >> 18),
                                 logC - (float)(r & QMASK) * (1.0f/QSCALE));
                    }
                    scnt[b] = 0;
                }
            } else scnt[b] = c;
        }
        __syncthreads();
    }

    // ---- final flush: write remainder (64B-padded), record valid counts ----
    for (int b = tid; b < nbuckets; b += 256) {
        int c = scnt[b]; if (c > STAGE_S) c = STAGE_S;
        int have = cnum[b];
        int valid = have << 4;
        int nfull = (c + 15) >> 4;              // 0..2 chunks
        int fit = (cappb >> 4) - have;
        int nw = nfull < fit ? nfull : fit;
        if (nw > 0) {
            unsigned* dst = pairs +
                (((long long)b * NBLK + blk) << cap_shift) + (have << 4);
            const uint4* s4 = (const uint4*)&stage[b * STAGE_S];
            uint4* d4 = (uint4*)dst;
            for (int ch = 0; ch < nw; ++ch) {
                d4[ch*4+0]=s4[ch*4+0]; d4[ch*4+1]=s4[ch*4+1];
                d4[ch*4+2]=s4[ch*4+2]; d4[ch*4+3]=s4[ch*4+3];
            }
            int v2 = nw << 4; if (v2 > c) v2 = c;
            valid += v2;
        }
        for (int i = (nw << 4); i < c; ++i) {   // unfit tail -> ovf (rare)
            unsigned r = stage[b*STAGE_S + i];
            ovf_push(ovf, ovf_cnt, ovcap,
                     ((unsigned)b << SLOT_BITS) | (r >> 18),
                     logC - (float)(r & QMASK) * (1.0f/QSCALE));
        }
        fill[b * NBLK + blk] = valid;
    }
}

__global__ __launch_bounds__(512) void reduce_kernel(
        const unsigned* __restrict__ pairs, const int* __restrict__ fill,
        const uint2* __restrict__ ovf, const int* __restrict__ ovf_cnt, int ovcap,
        const float* __restrict__ thetas, float* __restrict__ out,
        long long n_out, int nbuckets, int cap_shift) {
    __shared__ float acc[SLOTS];   // 64 KB
    __shared__ int cnts[NBLK];     // 2 KB
    const int tid = threadIdx.x;
    const int b = blockIdx.x;

    for (int s = tid; s < SLOTS; s += 512) acc[s] = 0.0f;
    if (tid < NBLK) cnts[tid] = fill[(long long)b * NBLK + tid];
    __syncthreads();

    const float t1 = thetas[1];
    const float t0c = fminf(fmaxf(thetas[0], 0.0f), 1.0f);
    const float logC = logf(t0c * INV_SQRT_2PI / t1);
    const int cmask = (1 << cap_shift) - 1;

    // stream the whole contiguous span for this bucket: NBLK<<cap_shift recs
    const uint4* p4 = (const uint4*)(pairs + ((long long)b * NBLK << cap_shift));
    int total4 = (NBLK << cap_shift) >> 2;
    for (int g = tid; g < total4; g += 512) {
        uint4 r = p4[g];
        int o = g << 2;
        int blk = o >> cap_shift;
        int pos = o & cmask;
        int v = cnts[blk] - pos;    // records valid in this uint4: clamp to 0..4
        if (v > 0) {
            atomicAdd(&acc[r.x >> 18], logC - (float)(r.x & QMASK) * (1.0f/QSCALE));
            if (v > 1) atomicAdd(&acc[r.y >> 18], logC - (float)(r.y & QMASK) * (1.0f/QSCALE));
            if (v > 2) atomicAdd(&acc[r.z >> 18], logC - (float)(r.z & QMASK) * (1.0f/QSCALE));
            if (v > 3) atomicAdd(&acc[r.w >> 18], logC - (float)(r.w & QMASK) * (1.0f/QSCALE));
        }
    }
    __syncthreads();

    int no = *ovf_cnt; if (no > ovcap) no = ovcap;
    for (int i = tid; i < no; i += 512) {
        uint2 e = ovf[i];
        if ((int)(e.x >> SLOT_BITS) == b)
            atomicAdd(&acc[e.x & (SLOTS - 1)], __uint_as_float(e.y));
    }
    __syncthreads();

    const float cond = 1.0f - t0c;
    long long obase = (long long)b << SLOT_BITS;
    for (int s = tid; s < SLOTS; s += 512) {
        long long o = obase + s;
        if (o < n_out) out[o] = cond * expf(acc[s]);
    }
}

// ---- fallback path: direct global atomics (R1) ----
__global__ void init_zero_kernel(float* __restrict__ out, int n) {
    int i = blockIdx.x * blockDim.x + threadIdx.x;
    int stride = gridDim.x * blockDim.x;
    for (; i < n; i += stride) out[i] = 0.0f;
}
__global__ void scatter_log_kernel(const int* __restrict__ idx,
                                   const float* __restrict__ vals,
                                   const float* __restrict__ thetas,
                                   float* __restrict__ acc, int n) {
    float t1 = thetas[1], t2 = thetas[2];
    float t0c = fminf(fmaxf(thetas[0], 0.0f), 1.0f);
    float logC = logf(t0c * INV_SQRT_2PI / t1);
    float inv_t1 = 1.0f / t1;
    int i = blockIdx.x * blockDim.x + threadIdx.x;
    int stride = gridDim.x * blockDim.x;
    for (; i < n; i += stride) {
        float z = (vals[i] - t2) * inv_t1;
        atomicAdd(&acc[idx[i]], fmaf(-0.5f * z, z, logC));
    }
}
__global__ void finalize_kernel(float* __restrict__ out,
                                const float* __restrict__ thetas, int n) {
    float t0c = fminf(fmaxf(thetas[0], 0.0f), 1.0f);
    float cond = 1.0f - t0c;
    int i = blockIdx.x * blockDim.x + threadIdx.x;
    int stride = gridDim.x * blockDim.x;
    for (; i < n; i += stride) out[i] = cond * expf(out[i]);
}

extern "C" void kernel_launch(void* const* d_in, const int* in_sizes, int n_in,
                              void* d_out, int out_size, void* d_ws, size_t ws_size,
                              hipStream_t stream) {
    // inputs: [0]=batch (scalar), [1]=idx (int32), [2]=vals (f32), [3]=thetas (f32 x3)
    const int*   idx    = (const int*)d_in[1];
    const float* vals   = (const float*)d_in[2];
    const float* thetas = (const float*)d_in[3];
    float*       out    = (float*)d_out;

    int n_events = in_sizes[1];
    long long n_out = out_size;
    int nbuckets = (int)((n_out + SLOTS - 1) >> SLOT_BITS);

    // geometry
    long long tiles_total = ((long long)n_events + TILE - 1) / TILE;
    long long tpb = (tiles_total + NBLK - 1) / NBLK;
    int epb = (int)(tpb * TILE);
    long long avg = nbuckets > 0 ? (epb + nbuckets - 1) / nbuckets : 1;
    long long want = avg + avg / 2 + 32;        // Poisson mean avg, >>6 sigma
    int cap_shift = 6;
    while ((1LL << cap_shift) < want && cap_shift < 20) ++cap_shift;
    long long cappb = 1LL << cap_shift;

    size_t pairs_b = (size_t)NBLK * nbuckets * cappb * 4;
    size_t fill_b  = (size_t)NBLK * nbuckets * 4;
    size_t head    = pairs_b + fill_b + 64;
    bool fast = (nbuckets > 0) && (nbuckets <= NB_MAX) && (n_events > 0) &&
                (ws_size >= head + 64 * 1024);

    if (fast) {
        unsigned* pairs = (unsigned*)d_ws;
        int* fill = (int*)((char*)d_ws + pairs_b);
        int* ovf_cnt = (int*)((char*)d_ws + pairs_b + fill_b);
        uint2* ovf = (uint2*)((char*)d_ws + head);
        long long ovcap_ll = (long long)((ws_size - head) / 8);
        int ovcap = (int)(ovcap_ll > 4194304 ? 4194304 : ovcap_ll);

        zero_ovf_kernel<<<1, 1, 0, stream>>>(ovf_cnt);
        bin_kernel<<<NBLK, 256, 0, stream>>>(idx, vals, thetas, pairs, fill,
                                             ovf, ovf_cnt, ovcap,
                                             n_events, nbuckets, cap_shift, epb);
        reduce_kernel<<<nbuckets, 512, 0, stream>>>(pairs, fill, ovf, ovf_cnt,
                                                    ovcap, thetas, out,
                                                    n_out, nbuckets, cap_shift);
    } else {
        const int BLOCK = 256;
        int grid_out = min((int)((n_out + BLOCK - 1) / BLOCK), 2048);
        int grid_ev  = min((n_events + BLOCK - 1) / BLOCK, 2048);
        init_zero_kernel<<<grid_out, BLOCK, 0, stream>>>(out, (int)n_out);
        scatter_log_kernel<<<grid_ev, BLOCK, 0, stream>>>(idx, vals, thetas, out, n_events);
        finalize_kernel<<<grid_out, BLOCK, 0, stream>>>(out, thetas, (int)n_out);
    }
}

// Round 6
// 185.626 us; speedup vs baseline: 4.4474x; 1.0200x over previous
//
#include <hip/hip_runtime.h>

// out[i] = cond * prod_{e: idx[e]==i} factor[e];  cond = 1 - clip(t0,0,1)
// log(factor) = logC - u,  u = 0.5*((v-t2)/t1)^2,  logC = log(t0c*INV_SQRT_2PI/t1)
//
// R6: pairs block-major [blk][bucket][cappb] (bin write locality, R4) +
// reduce at 1024 threads with per-wave segment streaming (per-lane scalar
// records, coalesced 256B loads), counts in LDS, 2-deep software pipeline
// prefetching the next segment. zero_ovf via hipMemsetAsync.

#define INV_SQRT_2PI 0.39894246f  // 1/sqrt(2*3.14159) (matches reference)
#define SLOT_BITS 14
#define SLOTS (1 << SLOT_BITS)
#define NB_MAX 512          // max buckets for fast path
#define NBLK 512            // binning blocks (block-private regions)
#define TILE 2048           // events per block-tile (8 per thread)
#define STAGE_S 28          // stage depth per bucket (records)
#define QSCALE 8192.0f
#define QMASK 0x3FFFFu      // 18 bits

__device__ __forceinline__ void ovf_push(uint2* ovf, int* ovf_cnt, int ovcap,
                                         unsigned gslot, float lf) {
    int op = atomicAdd(ovf_cnt, 1);
    if (op < ovcap) ovf[op] = make_uint2(gslot, __float_as_uint(lf));
}

__global__ __launch_bounds__(256) void bin_kernel(
        const int* __restrict__ idx, const float* __restrict__ vals,
        const float* __restrict__ thetas,
        unsigned* __restrict__ pairs,  // [NBLK][nbuckets][cappb]
        int* __restrict__ fill,        // [NBLK][nbuckets] valid counts
        uint2* __restrict__ ovf, int* __restrict__ ovf_cnt, int ovcap,
        int n, int nbuckets, int cap_shift, int epb) {
    __shared__ unsigned stage[NB_MAX * STAGE_S];  // 56 KB
    __shared__ int scnt[NB_MAX];
    __shared__ int cnum[NB_MAX];                  // 64B chunks written

    const int tid = threadIdx.x;
    const int blk = blockIdx.x;
    const int cappb = 1 << cap_shift;
    long long start = (long long)blk * epb;
    long long end = start + epb;
    if (end > n) end = n;

    for (int b = tid; b < nbuckets; b += 256) { scnt[b] = 0; cnum[b] = 0; }
    __syncthreads();

    const float t1 = thetas[1], t2 = thetas[2];
    const float t0c = fminf(fmaxf(thetas[0], 0.0f), 1.0f);
    const float logC = logf(t0c * INV_SQRT_2PI / t1);
    const float inv_t1 = 1.0f / t1;

    for (long long ts = start; ts < end; ts += TILE) {
        long long te = ts + TILE; if (te > end) te = end;
        long long base = ts + (long long)tid * 8;

        // ---- scatter 8 events into LDS stage ----
        int   ks[8]; float vs[8]; int cnt_ev = 0;
        if (base + 8 <= te) {
            int4 k0 = *(const int4*)(idx + base);
            int4 k1 = *(const int4*)(idx + base + 4);
            float4 v0 = *(const float4*)(vals + base);
            float4 v1 = *(const float4*)(vals + base + 4);
            ks[0]=k0.x;ks[1]=k0.y;ks[2]=k0.z;ks[3]=k0.w;
            ks[4]=k1.x;ks[5]=k1.y;ks[6]=k1.z;ks[7]=k1.w;
            vs[0]=v0.x;vs[1]=v0.y;vs[2]=v0.z;vs[3]=v0.w;
            vs[4]=v1.x;vs[5]=v1.y;vs[6]=v1.z;vs[7]=v1.w;
            cnt_ev = 8;
        } else if (base < te) {
            for (long long e = base; e < te; ++e) {
                ks[cnt_ev] = idx[e]; vs[cnt_ev] = vals[e]; ++cnt_ev;
            }
        }
        for (int j = 0; j < cnt_ev; ++j) {
            unsigned uk = (unsigned)ks[j];
            int b = uk >> SLOT_BITS;
            if (b >= nbuckets) continue;
            float z = (vs[j] - t2) * inv_t1;
            float u = 0.5f * z * z;
            unsigned q = __float2uint_rn(fminf(u * QSCALE, (float)QMASK));
            unsigned rec = ((uk & (SLOTS - 1)) << 18) | q;
            int pos = atomicAdd(&scnt[b], 1);
            if (pos < STAGE_S) stage[b * STAGE_S + pos] = rec;
            else ovf_push(ovf, ovf_cnt, ovcap, uk, logC - u);
        }
        __syncthreads();

        // ---- flush full 64B chunks (block-major dst: write locality) ----
        for (int b = tid; b < nbuckets; b += 256) {
            int c = scnt[b]; if (c > STAGE_S) c = STAGE_S;
            if (c >= 16) {
                int have = cnum[b];
                if (have < (cappb >> 4)) {
                    unsigned* dst = pairs +
                        (((long long)blk * nbuckets + b) << cap_shift) + (have << 4);
                    const uint4* s4 = (const uint4*)&stage[b * STAGE_S];
                    uint4* d4 = (uint4*)dst;
                    d4[0]=s4[0]; d4[1]=s4[1]; d4[2]=s4[2]; d4[3]=s4[3];
                    cnum[b] = have + 1;
                    int rem = c - 16;
                    for (int i = 0; i < rem; ++i)
                        stage[b*STAGE_S + i] = stage[b*STAGE_S + 16 + i];
                    scnt[b] = rem;
                } else {  // region full (shouldn't happen): spill all to ovf
                    for (int i = 0; i < c; ++i) {
                        unsigned r = stage[b*STAGE_S + i];
                        ovf_push(ovf, ovf_cnt, ovcap,
                                 ((unsigned)b << SLOT_BITS) | (r >> 18),
                                 logC - (float)(r & QMASK) * (1.0f/QSCALE));
                    }
                    scnt[b] = 0;
                }
            } else scnt[b] = c;
        }
        __syncthreads();
    }

    // ---- final flush: write remainder (64B-padded), record valid counts ----
    for (int b = tid; b < nbuckets; b += 256) {
        int c = scnt[b]; if (c > STAGE_S) c = STAGE_S;
        int have = cnum[b];
        int valid = have << 4;
        int nfull = (c + 15) >> 4;              // 0..2 chunks
        int fit = (cappb >> 4) - have;
        int nw = nfull < fit ? nfull : fit;
        if (nw > 0) {
            unsigned* dst = pairs +
                (((long long)blk * nbuckets + b) << cap_shift) + (have << 4);
            const uint4* s4 = (const uint4*)&stage[b * STAGE_S];
            uint4* d4 = (uint4*)dst;
            for (int ch = 0; ch < nw; ++ch) {
                d4[ch*4+0]=s4[ch*4+0]; d4[ch*4+1]=s4[ch*4+1];
                d4[ch*4+2]=s4[ch*4+2]; d4[ch*4+3]=s4[ch*4+3];
            }
            int v2 = nw << 4; if (v2 > c) v2 = c;
            valid += v2;
        }
        for (int i = (nw << 4); i < c; ++i) {   // unfit tail -> ovf (rare)
            unsigned r = stage[b*STAGE_S + i];
            ovf_push(ovf, ovf_cnt, ovcap,
                     ((unsigned)b << SLOT_BITS) | (r >> 18),
                     logC - (float)(r & QMASK) * (1.0f/QSCALE));
        }
        fill[blk * nbuckets + b] = valid;
    }
}

__global__ __launch_bounds__(1024) void reduce_kernel(
        const unsigned* __restrict__ pairs, const int* __restrict__ fill,
        const uint2* __restrict__ ovf, const int* __restrict__ ovf_cnt, int ovcap,
        const float* __restrict__ thetas, float* __restrict__ out,
        long long n_out, int nbuckets, int cap_shift) {
    __shared__ float acc[SLOTS];   // 64 KB
    __shared__ int cnts[NBLK];     // 2 KB
    const int tid = threadIdx.x;
    const int b = blockIdx.x;

    for (int s = tid; s < SLOTS; s += 1024) acc[s] = 0.0f;
    for (int s = tid; s < NBLK; s += 1024)
        cnts[s] = fill[((long long)s * nbuckets + b)];
    __syncthreads();

    const float t1 = thetas[1];
    const float t0c = fminf(fmaxf(thetas[0], 0.0f), 1.0f);
    const float logC = logf(t0c * INV_SQRT_2PI / t1);

    const int wave = tid >> 6, lane = tid & 63;
    const int NW = 16;   // 1024 threads

    // per-wave segment streaming, 2-deep software pipeline
    int s = wave;
    unsigned a0 = 0, a1 = 0; int ccur = 0; const unsigned* pcur = 0;
    if (s < NBLK) {
        pcur = pairs + (((long long)s * nbuckets + b) << cap_shift);
        ccur = cnts[s];
        a0 = pcur[lane];
        if (ccur > 64) a1 = pcur[64 + lane];
    }
    while (s < NBLK) {
        int sn = s + NW;
        unsigned b0 = 0, b1 = 0; int cn = 0; const unsigned* pn = 0;
        if (sn < NBLK) {
            pn = pairs + (((long long)sn * nbuckets + b) << cap_shift);
            cn = cnts[sn];
            b0 = pn[lane];
            if (cn > 64) b1 = pn[64 + lane];
        }
        // process current segment
        if (lane < ccur)
            atomicAdd(&acc[a0 >> 18], logC - (float)(a0 & QMASK) * (1.0f/QSCALE));
        if (ccur > 64 && 64 + lane < ccur)
            atomicAdd(&acc[a1 >> 18], logC - (float)(a1 & QMASK) * (1.0f/QSCALE));
        // rare: cnt beyond 128 (only if cap_shift > 7)
        for (int r = 128 + lane; r < ccur; r += 64) {
            unsigned rec = pcur[r];
            atomicAdd(&acc[rec >> 18], logC - (float)(rec & QMASK) * (1.0f/QSCALE));
        }
        a0 = b0; a1 = b1; ccur = cn; pcur = pn; s = sn;
    }
    __syncthreads();

    int no = *ovf_cnt; if (no > ovcap) no = ovcap;
    for (int i = tid; i < no; i += 1024) {
        uint2 e = ovf[i];
        if ((int)(e.x >> SLOT_BITS) == b)
            atomicAdd(&acc[e.x & (SLOTS - 1)], __uint_as_float(e.y));
    }
    __syncthreads();

    const float cond = 1.0f - t0c;
    long long obase = (long long)b << SLOT_BITS;
    for (int ss = tid; ss < SLOTS; ss += 1024) {
        long long o = obase + ss;
        if (o < n_out) out[o] = cond * expf(acc[ss]);
    }
}

// ---- fallback path: direct global atomics (R1) ----
__global__ void init_zero_kernel(float* __restrict__ out, int n) {
    int i = blockIdx.x * blockDim.x + threadIdx.x;
    int stride = gridDim.x * blockDim.x;
    for (; i < n; i += stride) out[i] = 0.0f;
}
__global__ void scatter_log_kernel(const int* __restrict__ idx,
                                   const float* __restrict__ vals,
                                   const float* __restrict__ thetas,
                                   float* __restrict__ acc, int n) {
    float t1 = thetas[1], t2 = thetas[2];
    float t0c = fminf(fmaxf(thetas[0], 0.0f), 1.0f);
    float logC = logf(t0c * INV_SQRT_2PI / t1);
    float inv_t1 = 1.0f / t1;
    int i = blockIdx.x * blockDim.x + threadIdx.x;
    int stride = gridDim.x * blockDim.x;
    for (; i < n; i += stride) {
        float z = (vals[i] - t2) * inv_t1;
        atomicAdd(&acc[idx[i]], fmaf(-0.5f * z, z, logC));
    }
}
__global__ void finalize_kernel(float* __restrict__ out,
                                const float* __restrict__ thetas, int n) {
    float t0c = fminf(fmaxf(thetas[0], 0.0f), 1.0f);
    float cond = 1.0f - t0c;
    int i = blockIdx.x * blockDim.x + threadIdx.x;
    int stride = gridDim.x * blockDim.x;
    for (; i < n; i += stride) out[i] = cond * expf(out[i]);
}

extern "C" void kernel_launch(void* const* d_in, const int* in_sizes, int n_in,
                              void* d_out, int out_size, void* d_ws, size_t ws_size,
                              hipStream_t stream) {
    // inputs: [0]=batch (scalar), [1]=idx (int32), [2]=vals (f32), [3]=thetas (f32 x3)
    const int*   idx    = (const int*)d_in[1];
    const float* vals   = (const float*)d_in[2];
    const float* thetas = (const float*)d_in[3];
    float*       out    = (float*)d_out;

    int n_events = in_sizes[1];
    long long n_out = out_size;
    int nbuckets = (int)((n_out + SLOTS - 1) >> SLOT_BITS);

    // geometry
    long long tiles_total = ((long long)n_events + TILE - 1) / TILE;
    long long tpb = (tiles_total + NBLK - 1) / NBLK;
    int epb = (int)(tpb * TILE);
    long long avg = nbuckets > 0 ? (epb + nbuckets - 1) / nbuckets : 1;
    long long want = avg + avg / 2 + 32;        // Poisson mean avg, >>6 sigma
    int cap_shift = 6;
    while ((1LL << cap_shift) < want && cap_shift < 20) ++cap_shift;
    long long cappb = 1LL << cap_shift;

    size_t pairs_b = (size_t)NBLK * nbuckets * cappb * 4;
    size_t fill_b  = (size_t)NBLK * nbuckets * 4;
    size_t head    = pairs_b + fill_b + 64;
    bool fast = (nbuckets > 0) && (nbuckets <= NB_MAX) && (n_events > 0) &&
                (ws_size >= head + 64 * 1024);

    if (fast) {
        unsigned* pairs = (unsigned*)d_ws;
        int* fill = (int*)((char*)d_ws + pairs_b);
        int* ovf_cnt = (int*)((char*)d_ws + pairs_b + fill_b);
        uint2* ovf = (uint2*)((char*)d_ws + head);
        long long ovcap_ll = (long long)((ws_size - head) / 8);
        int ovcap = (int)(ovcap_ll > 4194304 ? 4194304 : ovcap_ll);

        hipMemsetAsync(ovf_cnt, 0, sizeof(int), stream);
        bin_kernel<<<NBLK, 256, 0, stream>>>(idx, vals, thetas, pairs, fill,
                                             ovf, ovf_cnt, ovcap,
                                             n_events, nbuckets, cap_shift, epb);
        reduce_kernel<<<nbuckets, 1024, 0, stream>>>(pairs, fill, ovf, ovf_cnt,
                                                     ovcap, thetas, out,
                                                     n_out, nbuckets, cap_shift);
    } else {
        const int BLOCK = 256;
        int grid_out = min((int)((n_out + BLOCK - 1) / BLOCK), 2048);
        int grid_ev  = min((n_events + BLOCK - 1) / BLOCK, 2048);
        init_zero_kernel<<<grid_out, BLOCK, 0, stream>>>(out, (int)n_out);
        scatter_log_kernel<<<grid_ev, BLOCK, 0, stream>>>(idx, vals, thetas, out, n_events);
        finalize_kernel<<<grid_out, BLOCK, 0, stream>>>(out, thetas, (int)n_out);
    }
}

// Round 7
// 126.869 us; speedup vs baseline: 6.5071x; 1.4631x over previous
//
#include <hip/hip_runtime.h>

// out[i] = cond * prod_{e: idx[e]==i} factor[e];  cond = 1 - clip(t0,0,1)
// log(factor) = logC - u,  u = 0.5*((v-t2)/t1)^2,  logC = log(t0c*INV_SQRT_2PI/t1)
//
// R7: reduce rewritten: (1) no LDS reads in hot loop (counts preloaded into
// lanes, consumed via readlane -> ds_add_u32 never drained by lgkmcnt),
// (2) packed integer LDS atomics: acc += (1<<25)|q; finalize
// count*logC - sum_q/QSCALE, (3) region swizzle ((b+blk)&mask) spreads a
// bucket's 512 segments across channels while bin keeps private-window
// write locality. Records: (slot:14 << 18) | q:18, q = rint(u*QSCALE).

#define INV_SQRT_2PI 0.39894246f  // 1/sqrt(2*3.14159) (matches reference)
#define SLOT_BITS 14
#define SLOTS (1 << SLOT_BITS)
#define NB_MAX 512          // max buckets for fast path
#define NBLK 512            // binning blocks (block-private regions)
#define TILE 2048           // events per block-tile (8 per thread)
#define STAGE_S 28          // stage depth per bucket (records)
#define QSCALE 8192.0f
#define QMASK 0x3FFFFu      // 18 bits

__device__ __forceinline__ long long region_idx(int blk, int b, int nbuckets,
                                                int swzmask) {
    int bb = swzmask ? ((b + blk) & swzmask) : b;
    return (long long)blk * nbuckets + bb;
}

__device__ __forceinline__ void ovf_push(uint2* ovf, int* ovf_cnt, int ovcap,
                                         unsigned gslot, unsigned q) {
    int op = atomicAdd(ovf_cnt, 1);
    if (op < ovcap) ovf[op] = make_uint2(gslot, q);
}

__global__ __launch_bounds__(256) void bin_kernel(
        const int* __restrict__ idx, const float* __restrict__ vals,
        const float* __restrict__ thetas,
        unsigned* __restrict__ pairs,  // [NBLK][nbuckets][cappb] (swizzled)
        int* __restrict__ fill,        // [NBLK][nbuckets] valid counts (swizzled)
        uint2* __restrict__ ovf, int* __restrict__ ovf_cnt, int ovcap,
        int n, int nbuckets, int cap_shift, int swzmask, int epb) {
    __shared__ unsigned stage[NB_MAX * STAGE_S];  // 56 KB
    __shared__ int scnt[NB_MAX];
    __shared__ int cnum[NB_MAX];                  // 64B chunks written

    const int tid = threadIdx.x;
    const int blk = blockIdx.x;
    const int cappb = 1 << cap_shift;
    long long start = (long long)blk * epb;
    long long end = start + epb;
    if (end > n) end = n;

    for (int b = tid; b < nbuckets; b += 256) { scnt[b] = 0; cnum[b] = 0; }
    __syncthreads();

    const float t1 = thetas[1], t2 = thetas[2];
    const float t0c = fminf(fmaxf(thetas[0], 0.0f), 1.0f);
    const float inv_t1 = 1.0f / t1;

    for (long long ts = start; ts < end; ts += TILE) {
        long long te = ts + TILE; if (te > end) te = end;
        long long base = ts + (long long)tid * 8;

        // ---- scatter 8 events into LDS stage ----
        int   ks[8]; float vs[8]; int cnt_ev = 0;
        if (base + 8 <= te) {
            int4 k0 = *(const int4*)(idx + base);
            int4 k1 = *(const int4*)(idx + base + 4);
            float4 v0 = *(const float4*)(vals + base);
            float4 v1 = *(const float4*)(vals + base + 4);
            ks[0]=k0.x;ks[1]=k0.y;ks[2]=k0.z;ks[3]=k0.w;
            ks[4]=k1.x;ks[5]=k1.y;ks[6]=k1.z;ks[7]=k1.w;
            vs[0]=v0.x;vs[1]=v0.y;vs[2]=v0.z;vs[3]=v0.w;
            vs[4]=v1.x;vs[5]=v1.y;vs[6]=v1.z;vs[7]=v1.w;
            cnt_ev = 8;
        } else if (base < te) {
            for (long long e = base; e < te; ++e) {
                ks[cnt_ev] = idx[e]; vs[cnt_ev] = vals[e]; ++cnt_ev;
            }
        }
        for (int j = 0; j < cnt_ev; ++j) {
            unsigned uk = (unsigned)ks[j];
            int b = uk >> SLOT_BITS;
            if (b >= nbuckets) continue;
            float z = (vs[j] - t2) * inv_t1;
            float u = 0.5f * z * z;
            unsigned q = __float2uint_rn(fminf(u * QSCALE, (float)QMASK));
            unsigned rec = ((uk & (SLOTS - 1)) << 18) | q;
            int pos = atomicAdd(&scnt[b], 1);
            if (pos < STAGE_S) stage[b * STAGE_S + pos] = rec;
            else ovf_push(ovf, ovf_cnt, ovcap, uk, q);
        }
        __syncthreads();

        // ---- flush full 64B chunks (block-private window) ----
        for (int b = tid; b < nbuckets; b += 256) {
            int c = scnt[b]; if (c > STAGE_S) c = STAGE_S;
            if (c >= 16) {
                int have = cnum[b];
                if (have < (cappb >> 4)) {
                    unsigned* dst = pairs +
                        (region_idx(blk, b, nbuckets, swzmask) << cap_shift) + (have << 4);
                    const uint4* s4 = (const uint4*)&stage[b * STAGE_S];
                    uint4* d4 = (uint4*)dst;
                    d4[0]=s4[0]; d4[1]=s4[1]; d4[2]=s4[2]; d4[3]=s4[3];
                    cnum[b] = have + 1;
                    int rem = c - 16;
                    for (int i = 0; i < rem; ++i)
                        stage[b*STAGE_S + i] = stage[b*STAGE_S + 16 + i];
                    scnt[b] = rem;
                } else {  // region full (shouldn't happen): spill all to ovf
                    for (int i = 0; i < c; ++i) {
                        unsigned r = stage[b*STAGE_S + i];
                        ovf_push(ovf, ovf_cnt, ovcap,
                                 ((unsigned)b << SLOT_BITS) | (r >> 18), r & QMASK);
                    }
                    scnt[b] = 0;
                }
            } else scnt[b] = c;
        }
        __syncthreads();
    }

    // ---- final flush: write remainder (64B-padded), record valid counts ----
    for (int b = tid; b < nbuckets; b += 256) {
        int c = scnt[b]; if (c > STAGE_S) c = STAGE_S;
        int have = cnum[b];
        int valid = have << 4;
        int nfull = (c + 15) >> 4;              // 0..2 chunks
        int fit = (cappb >> 4) - have;
        int nw = nfull < fit ? nfull : fit;
        if (nw > 0) {
            unsigned* dst = pairs +
                (region_idx(blk, b, nbuckets, swzmask) << cap_shift) + (have << 4);
            const uint4* s4 = (const uint4*)&stage[b * STAGE_S];
            uint4* d4 = (uint4*)dst;
            for (int ch = 0; ch < nw; ++ch) {
                d4[ch*4+0]=s4[ch*4+0]; d4[ch*4+1]=s4[ch*4+1];
                d4[ch*4+2]=s4[ch*4+2]; d4[ch*4+3]=s4[ch*4+3];
            }
            int v2 = nw << 4; if (v2 > c) v2 = c;
            valid += v2;
        }
        for (int i = (nw << 4); i < c; ++i) {   // unfit tail -> ovf (rare)
            unsigned r = stage[b*STAGE_S + i];
            ovf_push(ovf, ovf_cnt, ovcap,
                     ((unsigned)b << SLOT_BITS) | (r >> 18), r & QMASK);
        }
        fill[region_idx(blk, b, nbuckets, swzmask)] = valid;
    }
}

__global__ __launch_bounds__(1024) void reduce_kernel(
        const unsigned* __restrict__ pairs, const int* __restrict__ fill,
        const uint2* __restrict__ ovf, const int* __restrict__ ovf_cnt, int ovcap,
        const float* __restrict__ thetas, float* __restrict__ out,
        long long n_out, int nbuckets, int cap_shift, int swzmask) {
    __shared__ unsigned accu[SLOTS];   // 64 KB packed: count<<25 | sum_q
    const int tid = threadIdx.x;
    const int b = blockIdx.x;

    for (int s = tid; s < SLOTS; s += 1024) accu[s] = 0u;
    __syncthreads();

    const int wave = tid >> 6, lane = tid & 63;
    const int SEGS = NBLK / 16;   // 32 segments per wave

    // preload this wave's segment counts: lane i holds cnt(seg wave+i*16)
    int sl = wave + (lane & 31) * 16;
    int cntv = fill[region_idx(sl, b, nbuckets, swzmask)];

    // pipelined segment stream: records read unconditionally (2x256B/seg)
    const unsigned* pc = pairs +
        (region_idx(wave, b, nbuckets, swzmask) << cap_shift);
    unsigned a0 = pc[lane];
    unsigned a1 = pc[64 + lane];

    for (int i = 0; i < SEGS; ++i) {
        const unsigned* pn = pc; unsigned n0 = 0, n1 = 0;
        if (i < SEGS - 1) {
            int sn = wave + (i + 1) * 16;
            pn = pairs + (region_idx(sn, b, nbuckets, swzmask) << cap_shift);
            n0 = pn[lane];
            n1 = pn[64 + lane];
        }
        int ca = __builtin_amdgcn_readlane(cntv, i);
        if (lane < ca)      atomicAdd(&accu[a0 >> 18], (1u << 25) + (a0 & QMASK));
        if (64 + lane < ca) atomicAdd(&accu[a1 >> 18], (1u << 25) + (a1 & QMASK));
        for (int r = 128 + lane; r < ca; r += 64) {   // only if cap_shift > 7
            unsigned rec = pc[r];
            atomicAdd(&accu[rec >> 18], (1u << 25) + (rec & QMASK));
        }
        pc = pn; a0 = n0; a1 = n1;
    }
    __syncthreads();

    int no = *ovf_cnt; if (no > ovcap) no = ovcap;
    for (int i = tid; i < no; i += 1024) {
        uint2 e = ovf[i];
        if ((int)(e.x >> SLOT_BITS) == b)
            atomicAdd(&accu[e.x & (SLOTS - 1)], (1u << 25) + e.y);
    }
    __syncthreads();

    const float t1 = thetas[1];
    const float t0c = fminf(fmaxf(thetas[0], 0.0f), 1.0f);
    const float logC = logf(t0c * INV_SQRT_2PI / t1);
    const float cond = 1.0f - t0c;
    long long obase = (long long)b << SLOT_BITS;
    for (int ss = tid; ss < SLOTS; ss += 1024) {
        long long o = obase + ss;
        if (o < n_out) {
            unsigned av = accu[ss];
            float v = (float)(av >> 25) * logC
                    - (float)(av & 0x1FFFFFFu) * (1.0f / QSCALE);
            out[o] = cond * expf(v);
        }
    }
}

// ---- fallback path: direct global atomics (R1) ----
__global__ void init_zero_kernel(float* __restrict__ out, int n) {
    int i = blockIdx.x * blockDim.x + threadIdx.x;
    int stride = gridDim.x * blockDim.x;
    for (; i < n; i += stride) out[i] = 0.0f;
}
__global__ void scatter_log_kernel(const int* __restrict__ idx,
                                   const float* __restrict__ vals,
                                   const float* __restrict__ thetas,
                                   float* __restrict__ acc, int n) {
    float t1 = thetas[1], t2 = thetas[2];
    float t0c = fminf(fmaxf(thetas[0], 0.0f), 1.0f);
    float logC = logf(t0c * INV_SQRT_2PI / t1);
    float inv_t1 = 1.0f / t1;
    int i = blockIdx.x * blockDim.x + threadIdx.x;
    int stride = gridDim.x * blockDim.x;
    for (; i < n; i += stride) {
        float z = (vals[i] - t2) * inv_t1;
        atomicAdd(&acc[idx[i]], fmaf(-0.5f * z, z, logC));
    }
}
__global__ void finalize_kernel(float* __restrict__ out,
                                const float* __restrict__ thetas, int n) {
    float t0c = fminf(fmaxf(thetas[0], 0.0f), 1.0f);
    float cond = 1.0f - t0c;
    int i = blockIdx.x * blockDim.x + threadIdx.x;
    int stride = gridDim.x * blockDim.x;
    for (; i < n; i += stride) out[i] = cond * expf(out[i]);
}

extern "C" void kernel_launch(void* const* d_in, const int* in_sizes, int n_in,
                              void* d_out, int out_size, void* d_ws, size_t ws_size,
                              hipStream_t stream) {
    // inputs: [0]=batch (scalar), [1]=idx (int32), [2]=vals (f32), [3]=thetas (f32 x3)
    const int*   idx    = (const int*)d_in[1];
    const float* vals   = (const float*)d_in[2];
    const float* thetas = (const float*)d_in[3];
    float*       out    = (float*)d_out;

    int n_events = in_sizes[1];
    long long n_out = out_size;
    int nbuckets = (int)((n_out + SLOTS - 1) >> SLOT_BITS);

    // geometry
    long long tiles_total = ((long long)n_events + TILE - 1) / TILE;
    long long tpb = (tiles_total + NBLK - 1) / NBLK;
    int epb = (int)(tpb * TILE);
    long long avg = nbuckets > 0 ? (epb + nbuckets - 1) / nbuckets : 1;
    long long want = avg + avg / 2 + 32;        // Poisson mean avg, >>6 sigma
    int cap_shift = 6;
    while ((1LL << cap_shift) < want && cap_shift < 20) ++cap_shift;
    long long cappb = 1LL << cap_shift;
    int swzmask = (nbuckets > 0 && (nbuckets & (nbuckets - 1)) == 0)
                  ? nbuckets - 1 : 0;

    size_t pairs_b = (size_t)NBLK * nbuckets * cappb * 4;
    size_t fill_b  = (size_t)NBLK * nbuckets * 4;
    size_t head    = pairs_b + fill_b + 64;
    bool fast = (nbuckets > 0) && (nbuckets <= NB_MAX) && (n_events > 0) &&
                (ws_size >= head + 64 * 1024);

    if (fast) {
        unsigned* pairs = (unsigned*)d_ws;
        int* fill = (int*)((char*)d_ws + pairs_b);
        int* ovf_cnt = (int*)((char*)d_ws + pairs_b + fill_b);
        uint2* ovf = (uint2*)((char*)d_ws + head);
        long long ovcap_ll = (long long)((ws_size - head) / 8);
        int ovcap = (int)(ovcap_ll > 4194304 ? 4194304 : ovcap_ll);

        hipMemsetAsync(ovf_cnt, 0, sizeof(int), stream);
        bin_kernel<<<NBLK, 256, 0, stream>>>(idx, vals, thetas, pairs, fill,
                                             ovf, ovf_cnt, ovcap,
                                             n_events, nbuckets, cap_shift,
                                             swzmask, epb);
        reduce_kernel<<<nbuckets, 1024, 0, stream>>>(pairs, fill, ovf, ovf_cnt,
                                                     ovcap, thetas, out,
                                                     n_out, nbuckets, cap_shift,
                                                     swzmask);
    } else {
        const int BLOCK = 256;
        int grid_out = min((int)((n_out + BLOCK - 1) / BLOCK), 2048);
        int grid_ev  = min((n_events + BLOCK - 1) / BLOCK, 2048);
        init_zero_kernel<<<grid_out, BLOCK, 0, stream>>>(out, (int)n_out);
        scatter_log_kernel<<<grid_ev, BLOCK, 0, stream>>>(idx, vals, thetas, out, n_events);
        finalize_kernel<<<grid_out, BLOCK, 0, stream>>>(out, thetas, (int)n_out);
    }
}

// Round 8
// 100.362 us; speedup vs baseline: 8.2257x; 1.2641x over previous
//
#include <hip/hip_runtime.h>
#include <climits>

// out[i] = cond * prod_{e: idx[e]==i} factor[e];  cond = 1 - clip(t0,0,1)
// log(factor) = logC - u,  u = 0.5*((v-t2)/t1)^2,  logC = log(t0c*INV_SQRT_2PI/t1)
//
// R8: bin at 512 threads (16 waves/CU vs 8), per-tile phase split
// (compute records -> 4 back-to-back LDS atomics -> stores) to overlap
// LDS-atomic latency, and next-tile register prefetch of idx/vals.
// Reduce unchanged from R7 (packed int LDS atomics, readlane counts,
// region swizzle).

#define INV_SQRT_2PI 0.39894246f  // 1/sqrt(2*3.14159) (matches reference)
#define SLOT_BITS 14
#define SLOTS (1 << SLOT_BITS)
#define NB_MAX 512          // max buckets for fast path
#define NBLK 512            // binning blocks (block-private regions)
#define BTHREADS 512        // bin block threads
#define TILE 2048           // events per block-tile (4 per thread)
#define STAGE_S 28          // stage depth per bucket (records)
#define QSCALE 8192.0f
#define QMASK 0x3FFFFu      // 18 bits

__device__ __forceinline__ long long region_idx(int blk, int b, int nbuckets,
                                                int swzmask) {
    int bb = swzmask ? ((b + blk) & swzmask) : b;
    return (long long)blk * nbuckets + bb;
}

__device__ __forceinline__ void ovf_push(uint2* ovf, int* ovf_cnt, int ovcap,
                                         unsigned gslot, unsigned q) {
    int op = atomicAdd(ovf_cnt, 1);
    if (op < ovcap) ovf[op] = make_uint2(gslot, q);
}

struct Ev4 { int4 k; float4 v; int cnt; };

__device__ __forceinline__ Ev4 load4(const int* __restrict__ idx,
                                     const float* __restrict__ vals,
                                     long long base, long long te) {
    Ev4 r; r.cnt = 0;
    r.k = make_int4(0,0,0,0); r.v = make_float4(0,0,0,0);
    if (base + 4 <= te) {
        r.k = *(const int4*)(idx + base);
        r.v = *(const float4*)(vals + base);
        r.cnt = 4;
    } else if (base < te) {
        int c = (int)(te - base);
        int kk[4] = {0,0,0,0}; float vv[4] = {0,0,0,0};
        for (int i = 0; i < c; ++i) { kk[i] = idx[base+i]; vv[i] = vals[base+i]; }
        r.k = make_int4(kk[0],kk[1],kk[2],kk[3]);
        r.v = make_float4(vv[0],vv[1],vv[2],vv[3]);
        r.cnt = c;
    }
    return r;
}

__global__ __launch_bounds__(BTHREADS) void bin_kernel(
        const int* __restrict__ idx, const float* __restrict__ vals,
        const float* __restrict__ thetas,
        unsigned* __restrict__ pairs,  // [NBLK][nbuckets][cappb] (swizzled)
        int* __restrict__ fill,        // [NBLK][nbuckets] valid counts (swizzled)
        uint2* __restrict__ ovf, int* __restrict__ ovf_cnt, int ovcap,
        int n, int nbuckets, int cap_shift, int swzmask, int epb) {
    __shared__ unsigned stage[NB_MAX * STAGE_S];  // 56 KB
    __shared__ int scnt[NB_MAX];
    __shared__ int cnum[NB_MAX];                  // 64B chunks written

    const int tid = threadIdx.x;
    const int blk = blockIdx.x;
    const int cappb = 1 << cap_shift;
    long long start = (long long)blk * epb;
    long long end = start + epb;
    if (end > n) end = n;

    for (int b = tid; b < nbuckets; b += BTHREADS) { scnt[b] = 0; cnum[b] = 0; }
    __syncthreads();

    const float t1 = thetas[1], t2 = thetas[2];
    const float t0c = fminf(fmaxf(thetas[0], 0.0f), 1.0f);
    const float inv_t1 = 1.0f / t1;

    // prefetch tile 0
    Ev4 cur; cur.cnt = 0;
    if (start < end) {
        long long te0 = start + TILE; if (te0 > end) te0 = end;
        cur = load4(idx, vals, start + (long long)tid * 4, te0);
    }

    for (long long ts = start; ts < end; ts += TILE) {
        // ---- prefetch next tile while current is processed ----
        Ev4 nxt; nxt.cnt = 0;
        long long tsn = ts + TILE;
        if (tsn < end) {
            long long ten = tsn + TILE; if (ten > end) ten = end;
            nxt = load4(idx, vals, tsn + (long long)tid * 4, ten);
        }

        // ---- phase 1: compute records ----
        int   kk[4] = {cur.k.x, cur.k.y, cur.k.z, cur.k.w};
        float vv[4] = {cur.v.x, cur.v.y, cur.v.z, cur.v.w};
        int bs[4]; unsigned recs[4]; int pos[4];
        #pragma unroll
        for (int j = 0; j < 4; ++j) {
            unsigned uk = (unsigned)kk[j];
            bs[j] = (int)(uk >> SLOT_BITS);
            float z = (vv[j] - t2) * inv_t1;
            float u = 0.5f * z * z;
            unsigned q = __float2uint_rn(fminf(u * QSCALE, (float)QMASK));
            recs[j] = ((uk & (SLOTS - 1)) << 18) | q;
        }
        // ---- phase 2: independent atomics back-to-back ----
        #pragma unroll
        for (int j = 0; j < 4; ++j) {
            pos[j] = (j < cur.cnt && bs[j] < nbuckets)
                     ? atomicAdd(&scnt[bs[j]], 1) : INT_MAX;
        }
        // ---- phase 3: dependent stores ----
        #pragma unroll
        for (int j = 0; j < 4; ++j) {
            if (pos[j] == INT_MAX) continue;
            if (pos[j] < STAGE_S) stage[bs[j] * STAGE_S + pos[j]] = recs[j];
            else ovf_push(ovf, ovf_cnt, ovcap, (unsigned)kk[j], recs[j] & QMASK);
        }
        __syncthreads();

        // ---- flush full 64B chunks (block-private window) ----
        for (int b = tid; b < nbuckets; b += BTHREADS) {
            int c = scnt[b]; if (c > STAGE_S) c = STAGE_S;
            if (c >= 16) {
                int have = cnum[b];
                if (have < (cappb >> 4)) {
                    unsigned* dst = pairs +
                        (region_idx(blk, b, nbuckets, swzmask) << cap_shift) + (have << 4);
                    const uint4* s4 = (const uint4*)&stage[b * STAGE_S];
                    uint4* d4 = (uint4*)dst;
                    d4[0]=s4[0]; d4[1]=s4[1]; d4[2]=s4[2]; d4[3]=s4[3];
                    cnum[b] = have + 1;
                    int rem = c - 16;
                    for (int i = 0; i < rem; ++i)
                        stage[b*STAGE_S + i] = stage[b*STAGE_S + 16 + i];
                    scnt[b] = rem;
                } else {  // region full (shouldn't happen): spill all to ovf
                    for (int i = 0; i < c; ++i) {
                        unsigned r = stage[b*STAGE_S + i];
                        ovf_push(ovf, ovf_cnt, ovcap,
                                 ((unsigned)b << SLOT_BITS) | (r >> 18), r & QMASK);
                    }
                    scnt[b] = 0;
                }
            } else scnt[b] = c;
        }
        __syncthreads();
        cur = nxt;
    }

    // ---- final flush: write remainder (64B-padded), record valid counts ----
    for (int b = tid; b < nbuckets; b += BTHREADS) {
        int c = scnt[b]; if (c > STAGE_S) c = STAGE_S;
        int have = cnum[b];
        int valid = have << 4;
        int nfull = (c + 15) >> 4;              // 0..2 chunks
        int fit = (cappb >> 4) - have;
        int nw = nfull < fit ? nfull : fit;
        if (nw > 0) {
            unsigned* dst = pairs +
                (region_idx(blk, b, nbuckets, swzmask) << cap_shift) + (have << 4);
            const uint4* s4 = (const uint4*)&stage[b * STAGE_S];
            uint4* d4 = (uint4*)dst;
            for (int ch = 0; ch < nw; ++ch) {
                d4[ch*4+0]=s4[ch*4+0]; d4[ch*4+1]=s4[ch*4+1];
                d4[ch*4+2]=s4[ch*4+2]; d4[ch*4+3]=s4[ch*4+3];
            }
            int v2 = nw << 4; if (v2 > c) v2 = c;
            valid += v2;
        }
        for (int i = (nw << 4); i < c; ++i) {   // unfit tail -> ovf (rare)
            unsigned r = stage[b*STAGE_S + i];
            ovf_push(ovf, ovf_cnt, ovcap,
                     ((unsigned)b << SLOT_BITS) | (r >> 18), r & QMASK);
        }
        fill[region_idx(blk, b, nbuckets, swzmask)] = valid;
    }
}

__global__ __launch_bounds__(1024) void reduce_kernel(
        const unsigned* __restrict__ pairs, const int* __restrict__ fill,
        const uint2* __restrict__ ovf, const int* __restrict__ ovf_cnt, int ovcap,
        const float* __restrict__ thetas, float* __restrict__ out,
        long long n_out, int nbuckets, int cap_shift, int swzmask) {
    __shared__ unsigned accu[SLOTS];   // 64 KB packed: count<<25 | sum_q
    const int tid = threadIdx.x;
    const int b = blockIdx.x;

    for (int s = tid; s < SLOTS; s += 1024) accu[s] = 0u;
    __syncthreads();

    const int wave = tid >> 6, lane = tid & 63;
    const int SEGS = NBLK / 16;   // 32 segments per wave

    // preload this wave's segment counts: lane i holds cnt(seg wave+i*16)
    int sl = wave + (lane & 31) * 16;
    int cntv = fill[region_idx(sl, b, nbuckets, swzmask)];

    // pipelined segment stream: records read unconditionally (2x256B/seg)
    const unsigned* pc = pairs +
        (region_idx(wave, b, nbuckets, swzmask) << cap_shift);
    unsigned a0 = pc[lane];
    unsigned a1 = pc[64 + lane];

    for (int i = 0; i < SEGS; ++i) {
        const unsigned* pn = pc; unsigned n0 = 0, n1 = 0;
        if (i < SEGS - 1) {
            int sn = wave + (i + 1) * 16;
            pn = pairs + (region_idx(sn, b, nbuckets, swzmask) << cap_shift);
            n0 = pn[lane];
            n1 = pn[64 + lane];
        }
        int ca = __builtin_amdgcn_readlane(cntv, i);
        if (lane < ca)      atomicAdd(&accu[a0 >> 18], (1u << 25) + (a0 & QMASK));
        if (64 + lane < ca) atomicAdd(&accu[a1 >> 18], (1u << 25) + (a1 & QMASK));
        for (int r = 128 + lane; r < ca; r += 64) {   // only if cap_shift > 7
            unsigned rec = pc[r];
            atomicAdd(&accu[rec >> 18], (1u << 25) + (rec & QMASK));
        }
        pc = pn; a0 = n0; a1 = n1;
    }
    __syncthreads();

    int no = *ovf_cnt; if (no > ovcap) no = ovcap;
    for (int i = tid; i < no; i += 1024) {
        uint2 e = ovf[i];
        if ((int)(e.x >> SLOT_BITS) == b)
            atomicAdd(&accu[e.x & (SLOTS - 1)], (1u << 25) + e.y);
    }
    __syncthreads();

    const float t1 = thetas[1];
    const float t0c = fminf(fmaxf(thetas[0], 0.0f), 1.0f);
    const float logC = logf(t0c * INV_SQRT_2PI / t1);
    const float cond = 1.0f - t0c;
    long long obase = (long long)b << SLOT_BITS;
    for (int ss = tid; ss < SLOTS; ss += 1024) {
        long long o = obase + ss;
        if (o < n_out) {
            unsigned av = accu[ss];
            float v = (float)(av >> 25) * logC
                    - (float)(av & 0x1FFFFFFu) * (1.0f / QSCALE);
            out[o] = cond * expf(v);
        }
    }
}

// ---- fallback path: direct global atomics (R1) ----
__global__ void init_zero_kernel(float* __restrict__ out, int n) {
    int i = blockIdx.x * blockDim.x + threadIdx.x;
    int stride = gridDim.x * blockDim.x;
    for (; i < n; i += stride) out[i] = 0.0f;
}
__global__ void scatter_log_kernel(const int* __restrict__ idx,
                                   const float* __restrict__ vals,
                                   const float* __restrict__ thetas,
                                   float* __restrict__ acc, int n) {
    float t1 = thetas[1], t2 = thetas[2];
    float t0c = fminf(fmaxf(thetas[0], 0.0f), 1.0f);
    float logC = logf(t0c * INV_SQRT_2PI / t1);
    float inv_t1 = 1.0f / t1;
    int i = blockIdx.x * blockDim.x + threadIdx.x;
    int stride = gridDim.x * blockDim.x;
    for (; i < n; i += stride) {
        float z = (vals[i] - t2) * inv_t1;
        atomicAdd(&acc[idx[i]], fmaf(-0.5f * z, z, logC));
    }
}
__global__ void finalize_kernel(float* __restrict__ out,
                                const float* __restrict__ thetas, int n) {
    float t0c = fminf(fmaxf(thetas[0], 0.0f), 1.0f);
    float cond = 1.0f - t0c;
    int i = blockIdx.x * blockDim.x + threadIdx.x;
    int stride = gridDim.x * blockDim.x;
    for (; i < n; i += stride) out[i] = cond * expf(out[i]);
}

extern "C" void kernel_launch(void* const* d_in, const int* in_sizes, int n_in,
                              void* d_out, int out_size, void* d_ws, size_t ws_size,
                              hipStream_t stream) {
    // inputs: [0]=batch (scalar), [1]=idx (int32), [2]=vals (f32), [3]=thetas (f32 x3)
    const int*   idx    = (const int*)d_in[1];
    const float* vals   = (const float*)d_in[2];
    const float* thetas = (const float*)d_in[3];
    float*       out    = (float*)d_out;

    int n_events = in_sizes[1];
    long long n_out = out_size;
    int nbuckets = (int)((n_out + SLOTS - 1) >> SLOT_BITS);

    // geometry
    long long tiles_total = ((long long)n_events + TILE - 1) / TILE;
    long long tpb = (tiles_total + NBLK - 1) / NBLK;
    int epb = (int)(tpb * TILE);
    long long avg = nbuckets > 0 ? (epb + nbuckets - 1) / nbuckets : 1;
    long long want = avg + avg / 2 + 32;        // Poisson mean avg, >>6 sigma
    int cap_shift = 6;
    while ((1LL << cap_shift) < want && cap_shift < 20) ++cap_shift;
    long long cappb = 1LL << cap_shift;
    int swzmask = (nbuckets > 0 && (nbuckets & (nbuckets - 1)) == 0)
                  ? nbuckets - 1 : 0;

    size_t pairs_b = (size_t)NBLK * nbuckets * cappb * 4;
    size_t fill_b  = (size_t)NBLK * nbuckets * 4;
    size_t head    = pairs_b + fill_b + 64;
    bool fast = (nbuckets > 0) && (nbuckets <= NB_MAX) && (n_events > 0) &&
                (ws_size >= head + 64 * 1024);

    if (fast) {
        unsigned* pairs = (unsigned*)d_ws;
        int* fill = (int*)((char*)d_ws + pairs_b);
        int* ovf_cnt = (int*)((char*)d_ws + pairs_b + fill_b);
        uint2* ovf = (uint2*)((char*)d_ws + head);
        long long ovcap_ll = (long long)((ws_size - head) / 8);
        int ovcap = (int)(ovcap_ll > 4194304 ? 4194304 : ovcap_ll);

        hipMemsetAsync(ovf_cnt, 0, sizeof(int), stream);
        bin_kernel<<<NBLK, BTHREADS, 0, stream>>>(idx, vals, thetas, pairs, fill,
                                                  ovf, ovf_cnt, ovcap,
                                                  n_events, nbuckets, cap_shift,
                                                  swzmask, epb);
        reduce_kernel<<<nbuckets, 1024, 0, stream>>>(pairs, fill, ovf, ovf_cnt,
                                                     ovcap, thetas, out,
                                                     n_out, nbuckets, cap_shift,
                                                     swzmask);
    } else {
        const int BLOCK = 256;
        int grid_out = min((int)((n_out + BLOCK - 1) / BLOCK), 2048);
        int grid_ev  = min((n_events + BLOCK - 1) / BLOCK, 2048);
        init_zero_kernel<<<grid_out, BLOCK, 0, stream>>>(out, (int)n_out);
        scatter_log_kernel<<<grid_ev, BLOCK, 0, stream>>>(idx, vals, thetas, out, n_events);
        finalize_kernel<<<grid_out, BLOCK, 0, stream>>>(out, thetas, (int)n_out);
    }
}

// Round 9
// 100.345 us; speedup vs baseline: 8.2271x; 1.0002x over previous
//
#include <hip/hip_runtime.h>
#include <climits>

// out[i] = cond * prod_{e: idx[e]==i} factor[e];  cond = 1 - clip(t0,0,1)
// log(factor) = logC - u,  u = 0.5*((v-t2)/t1)^2,  logC = log(t0c*INV_SQRT_2PI/t1)
//
// R9: bin's in-loop __syncthreads() replaced with raw
// {s_waitcnt lgkmcnt(0); s_barrier} (T4, HK pattern): __syncthreads emits a
// full vmcnt(0) drain that forced the next-tile prefetch + flush stores to
// retire inside every tile. Raw barrier keeps vmem in flight across tiles;
// only LDS visibility (lgkmcnt) is required at the barriers.
// Rest identical to R8 (512-thread bin, phase-split atomics, prefetch;
// reduce: packed int LDS atomics, readlane counts, region swizzle).

#define INV_SQRT_2PI 0.39894246f  // 1/sqrt(2*3.14159) (matches reference)
#define SLOT_BITS 14
#define SLOTS (1 << SLOT_BITS)
#define NB_MAX 512          // max buckets for fast path
#define NBLK 512            // binning blocks (block-private regions)
#define BTHREADS 512        // bin block threads
#define TILE 2048           // events per block-tile (4 per thread)
#define STAGE_S 28          // stage depth per bucket (records)
#define QSCALE 8192.0f
#define QMASK 0x3FFFFu      // 18 bits

// LDS-only barrier: waits DS ops, leaves vmem (prefetch loads, flush
// stores) in flight across the barrier.
#define LDS_BAR() do {                                        \
    asm volatile("s_waitcnt lgkmcnt(0)" ::: "memory");        \
    __builtin_amdgcn_s_barrier();                             \
} while (0)

__device__ __forceinline__ long long region_idx(int blk, int b, int nbuckets,
                                                int swzmask) {
    int bb = swzmask ? ((b + blk) & swzmask) : b;
    return (long long)blk * nbuckets + bb;
}

__device__ __forceinline__ void ovf_push(uint2* ovf, int* ovf_cnt, int ovcap,
                                         unsigned gslot, unsigned q) {
    int op = atomicAdd(ovf_cnt, 1);
    if (op < ovcap) ovf[op] = make_uint2(gslot, q);
}

struct Ev4 { int4 k; float4 v; int cnt; };

__device__ __forceinline__ Ev4 load4(const int* __restrict__ idx,
                                     const float* __restrict__ vals,
                                     long long base, long long te) {
    Ev4 r; r.cnt = 0;
    r.k = make_int4(0,0,0,0); r.v = make_float4(0,0,0,0);
    if (base + 4 <= te) {
        r.k = *(const int4*)(idx + base);
        r.v = *(const float4*)(vals + base);
        r.cnt = 4;
    } else if (base < te) {
        int c = (int)(te - base);
        int kk[4] = {0,0,0,0}; float vv[4] = {0,0,0,0};
        for (int i = 0; i < c; ++i) { kk[i] = idx[base+i]; vv[i] = vals[base+i]; }
        r.k = make_int4(kk[0],kk[1],kk[2],kk[3]);
        r.v = make_float4(vv[0],vv[1],vv[2],vv[3]);
        r.cnt = c;
    }
    return r;
}

__global__ __launch_bounds__(BTHREADS) void bin_kernel(
        const int* __restrict__ idx, const float* __restrict__ vals,
        const float* __restrict__ thetas,
        unsigned* __restrict__ pairs,  // [NBLK][nbuckets][cappb] (swizzled)
        int* __restrict__ fill,        // [NBLK][nbuckets] valid counts (swizzled)
        uint2* __restrict__ ovf, int* __restrict__ ovf_cnt, int ovcap,
        int n, int nbuckets, int cap_shift, int swzmask, int epb) {
    __shared__ unsigned stage[NB_MAX * STAGE_S];  // 56 KB
    __shared__ int scnt[NB_MAX];
    __shared__ int cnum[NB_MAX];                  // 64B chunks written

    const int tid = threadIdx.x;
    const int blk = blockIdx.x;
    const int cappb = 1 << cap_shift;
    long long start = (long long)blk * epb;
    long long end = start + epb;
    if (end > n) end = n;

    for (int b = tid; b < nbuckets; b += BTHREADS) { scnt[b] = 0; cnum[b] = 0; }
    __syncthreads();

    const float t1 = thetas[1], t2 = thetas[2];
    const float t0c = fminf(fmaxf(thetas[0], 0.0f), 1.0f);
    const float inv_t1 = 1.0f / t1;

    // prefetch tile 0
    Ev4 cur; cur.cnt = 0;
    if (start < end) {
        long long te0 = start + TILE; if (te0 > end) te0 = end;
        cur = load4(idx, vals, start + (long long)tid * 4, te0);
    }

    for (long long ts = start; ts < end; ts += TILE) {
        // ---- prefetch next tile while current is processed ----
        Ev4 nxt; nxt.cnt = 0;
        long long tsn = ts + TILE;
        if (tsn < end) {
            long long ten = tsn + TILE; if (ten > end) ten = end;
            nxt = load4(idx, vals, tsn + (long long)tid * 4, ten);
        }

        // ---- phase 1: compute records ----
        int   kk[4] = {cur.k.x, cur.k.y, cur.k.z, cur.k.w};
        float vv[4] = {cur.v.x, cur.v.y, cur.v.z, cur.v.w};
        int bs[4]; unsigned recs[4]; int pos[4];
        #pragma unroll
        for (int j = 0; j < 4; ++j) {
            unsigned uk = (unsigned)kk[j];
            bs[j] = (int)(uk >> SLOT_BITS);
            float z = (vv[j] - t2) * inv_t1;
            float u = 0.5f * z * z;
            unsigned q = __float2uint_rn(fminf(u * QSCALE, (float)QMASK));
            recs[j] = ((uk & (SLOTS - 1)) << 18) | q;
        }
        // ---- phase 2: independent atomics back-to-back ----
        #pragma unroll
        for (int j = 0; j < 4; ++j) {
            pos[j] = (j < cur.cnt && bs[j] < nbuckets)
                     ? atomicAdd(&scnt[bs[j]], 1) : INT_MAX;
        }
        // ---- phase 3: dependent stores ----
        #pragma unroll
        for (int j = 0; j < 4; ++j) {
            if (pos[j] == INT_MAX) continue;
            if (pos[j] < STAGE_S) stage[bs[j] * STAGE_S + pos[j]] = recs[j];
            else ovf_push(ovf, ovf_cnt, ovcap, (unsigned)kk[j], recs[j] & QMASK);
        }
        LDS_BAR();   // stage/scnt visible to flushers; vmem stays in flight

        // ---- flush full 64B chunks (block-private window) ----
        for (int b = tid; b < nbuckets; b += BTHREADS) {
            int c = scnt[b]; if (c > STAGE_S) c = STAGE_S;
            if (c >= 16) {
                int have = cnum[b];
                if (have < (cappb >> 4)) {
                    unsigned* dst = pairs +
                        (region_idx(blk, b, nbuckets, swzmask) << cap_shift) + (have << 4);
                    const uint4* s4 = (const uint4*)&stage[b * STAGE_S];
                    uint4* d4 = (uint4*)dst;
                    d4[0]=s4[0]; d4[1]=s4[1]; d4[2]=s4[2]; d4[3]=s4[3];
                    cnum[b] = have + 1;
                    int rem = c - 16;
                    for (int i = 0; i < rem; ++i)
                        stage[b*STAGE_S + i] = stage[b*STAGE_S + 16 + i];
                    scnt[b] = rem;
                } else {  // region full (shouldn't happen): spill all to ovf
                    for (int i = 0; i < c; ++i) {
                        unsigned r = stage[b*STAGE_S + i];
                        ovf_push(ovf, ovf_cnt, ovcap,
                                 ((unsigned)b << SLOT_BITS) | (r >> 18), r & QMASK);
                    }
                    scnt[b] = 0;
                }
            } else scnt[b] = c;
        }
        LDS_BAR();   // flush reads + scnt reset done before next tile's atomics
        cur = nxt;
    }

    // ---- final flush: write remainder (64B-padded), record valid counts ----
    for (int b = tid; b < nbuckets; b += BTHREADS) {
        int c = scnt[b]; if (c > STAGE_S) c = STAGE_S;
        int have = cnum[b];
        int valid = have << 4;
        int nfull = (c + 15) >> 4;              // 0..2 chunks
        int fit = (cappb >> 4) - have;
        int nw = nfull < fit ? nfull : fit;
        if (nw > 0) {
            unsigned* dst = pairs +
                (region_idx(blk, b, nbuckets, swzmask) << cap_shift) + (have << 4);
            const uint4* s4 = (const uint4*)&stage[b * STAGE_S];
            uint4* d4 = (uint4*)dst;
            for (int ch = 0; ch < nw; ++ch) {
                d4[ch*4+0]=s4[ch*4+0]; d4[ch*4+1]=s4[ch*4+1];
                d4[ch*4+2]=s4[ch*4+2]; d4[ch*4+3]=s4[ch*4+3];
            }
            int v2 = nw << 4; if (v2 > c) v2 = c;
            valid += v2;
        }
        for (int i = (nw << 4); i < c; ++i) {   // unfit tail -> ovf (rare)
            unsigned r = stage[b*STAGE_S + i];
            ovf_push(ovf, ovf_cnt, ovcap,
                     ((unsigned)b << SLOT_BITS) | (r >> 18), r & QMASK);
        }
        fill[region_idx(blk, b, nbuckets, swzmask)] = valid;
    }
}

__global__ __launch_bounds__(1024) void reduce_kernel(
        const unsigned* __restrict__ pairs, const int* __restrict__ fill,
        const uint2* __restrict__ ovf, const int* __restrict__ ovf_cnt, int ovcap,
        const float* __restrict__ thetas, float* __restrict__ out,
        long long n_out, int nbuckets, int cap_shift, int swzmask) {
    __shared__ unsigned accu[SLOTS];   // 64 KB packed: count<<25 | sum_q
    const int tid = threadIdx.x;
    const int b = blockIdx.x;

    for (int s = tid; s < SLOTS; s += 1024) accu[s] = 0u;
    __syncthreads();

    const int wave = tid >> 6, lane = tid & 63;
    const int SEGS = NBLK / 16;   // 32 segments per wave

    // preload this wave's segment counts: lane i holds cnt(seg wave+i*16)
    int sl = wave + (lane & 31) * 16;
    int cntv = fill[region_idx(sl, b, nbuckets, swzmask)];

    // pipelined segment stream: records read unconditionally (2x256B/seg)
    const unsigned* pc = pairs +
        (region_idx(wave, b, nbuckets, swzmask) << cap_shift);
    unsigned a0 = pc[lane];
    unsigned a1 = pc[64 + lane];

    for (int i = 0; i < SEGS; ++i) {
        const unsigned* pn = pc; unsigned n0 = 0, n1 = 0;
        if (i < SEGS - 1) {
            int sn = wave + (i + 1) * 16;
            pn = pairs + (region_idx(sn, b, nbuckets, swzmask) << cap_shift);
            n0 = pn[lane];
            n1 = pn[64 + lane];
        }
        int ca = __builtin_amdgcn_readlane(cntv, i);
        if (lane < ca)      atomicAdd(&accu[a0 >> 18], (1u << 25) + (a0 & QMASK));
        if (64 + lane < ca) atomicAdd(&accu[a1 >> 18], (1u << 25) + (a1 & QMASK));
        for (int r = 128 + lane; r < ca; r += 64) {   // only if cap_shift > 7
            unsigned rec = pc[r];
            atomicAdd(&accu[rec >> 18], (1u << 25) + (rec & QMASK));
        }
        pc = pn; a0 = n0; a1 = n1;
    }
    __syncthreads();

    int no = *ovf_cnt; if (no > ovcap) no = ovcap;
    for (int i = tid; i < no; i += 1024) {
        uint2 e = ovf[i];
        if ((int)(e.x >> SLOT_BITS) == b)
            atomicAdd(&accu[e.x & (SLOTS - 1)], (1u << 25) + e.y);
    }
    __syncthreads();

    const float t1 = thetas[1];
    const float t0c = fminf(fmaxf(thetas[0], 0.0f), 1.0f);
    const float logC = logf(t0c * INV_SQRT_2PI / t1);
    const float cond = 1.0f - t0c;
    long long obase = (long long)b << SLOT_BITS;
    for (int ss = tid; ss < SLOTS; ss += 1024) {
        long long o = obase + ss;
        if (o < n_out) {
            unsigned av = accu[ss];
            float v = (float)(av >> 25) * logC
                    - (float)(av & 0x1FFFFFFu) * (1.0f / QSCALE);
            out[o] = cond * expf(v);
        }
    }
}

// ---- fallback path: direct global atomics (R1) ----
__global__ void init_zero_kernel(float* __restrict__ out, int n) {
    int i = blockIdx.x * blockDim.x + threadIdx.x;
    int stride = gridDim.x * blockDim.x;
    for (; i < n; i += stride) out[i] = 0.0f;
}
__global__ void scatter_log_kernel(const int* __restrict__ idx,
                                   const float* __restrict__ vals,
                                   const float* __restrict__ thetas,
                                   float* __restrict__ acc, int n) {
    float t1 = thetas[1], t2 = thetas[2];
    float t0c = fminf(fmaxf(thetas[0], 0.0f), 1.0f);
    float logC = logf(t0c * INV_SQRT_2PI / t1);
    float inv_t1 = 1.0f / t1;
    int i = blockIdx.x * blockDim.x + threadIdx.x;
    int stride = gridDim.x * blockDim.x;
    for (; i < n; i += stride) {
        float z = (vals[i] - t2) * inv_t1;
        atomicAdd(&acc[idx[i]], fmaf(-0.5f * z, z, logC));
    }
}
__global__ void finalize_kernel(float* __restrict__ out,
                                const float* __restrict__ thetas, int n) {
    float t0c = fminf(fmaxf(thetas[0], 0.0f), 1.0f);
    float cond = 1.0f - t0c;
    int i = blockIdx.x * blockDim.x + threadIdx.x;
    int stride = gridDim.x * blockDim.x;
    for (; i < n; i += stride) out[i] = cond * expf(out[i]);
}

extern "C" void kernel_launch(void* const* d_in, const int* in_sizes, int n_in,
                              void* d_out, int out_size, void* d_ws, size_t ws_size,
                              hipStream_t stream) {
    // inputs: [0]=batch (scalar), [1]=idx (int32), [2]=vals (f32), [3]=thetas (f32 x3)
    const int*   idx    = (const int*)d_in[1];
    const float* vals   = (const float*)d_in[2];
    const float* thetas = (const float*)d_in[3];
    float*       out    = (float*)d_out;

    int n_events = in_sizes[1];
    long long n_out = out_size;
    int nbuckets = (int)((n_out + SLOTS - 1) >> SLOT_BITS);

    // geometry
    long long tiles_total = ((long long)n_events + TILE - 1) / TILE;
    long long tpb = (tiles_total + NBLK - 1) / NBLK;
    int epb = (int)(tpb * TILE);
    long long avg = nbuckets > 0 ? (epb + nbuckets - 1) / nbuckets : 1;
    long long want = avg + avg / 2 + 32;        // Poisson mean avg, >>6 sigma
    int cap_shift = 6;
    while ((1LL << cap_shift) < want && cap_shift < 20) ++cap_shift;
    long long cappb = 1LL << cap_shift;
    int swzmask = (nbuckets > 0 && (nbuckets & (nbuckets - 1)) == 0)
                  ? nbuckets - 1 : 0;

    size_t pairs_b = (size_t)NBLK * nbuckets * cappb * 4;
    size_t fill_b  = (size_t)NBLK * nbuckets * 4;
    size_t head    = pairs_b + fill_b + 64;
    bool fast = (nbuckets > 0) && (nbuckets <= NB_MAX) && (n_events > 0) &&
                (ws_size >= head + 64 * 1024);

    if (fast) {
        unsigned* pairs = (unsigned*)d_ws;
        int* fill = (int*)((char*)d_ws + pairs_b);
        int* ovf_cnt = (int*)((char*)d_ws + pairs_b + fill_b);
        uint2* ovf = (uint2*)((char*)d_ws + head);
        long long ovcap_ll = (long long)((ws_size - head) / 8);
        int ovcap = (int)(ovcap_ll > 4194304 ? 4194304 : ovcap_ll);

        hipMemsetAsync(ovf_cnt, 0, sizeof(int), stream);
        bin_kernel<<<NBLK, BTHREADS, 0, stream>>>(idx, vals, thetas, pairs, fill,
                                                  ovf, ovf_cnt, ovcap,
                                                  n_events, nbuckets, cap_shift,
                                                  swzmask, epb);
        reduce_kernel<<<nbuckets, 1024, 0, stream>>>(pairs, fill, ovf, ovf_cnt,
                                                     ovcap, thetas, out,
                                                     n_out, nbuckets, cap_shift,
                                                     swzmask);
    } else {
        const int BLOCK = 256;
        int grid_out = min((int)((n_out + BLOCK - 1) / BLOCK), 2048);
        int grid_ev  = min((n_events + BLOCK - 1) / BLOCK, 2048);
        init_zero_kernel<<<grid_out, BLOCK, 0, stream>>>(out, (int)n_out);
        scatter_log_kernel<<<grid_ev, BLOCK, 0, stream>>>(idx, vals, thetas, out, n_events);
        finalize_kernel<<<grid_out, BLOCK, 0, stream>>>(out, thetas, (int)n_out);
    }
}

// Round 10
// 98.482 us; speedup vs baseline: 8.3828x; 1.0189x over previous
//
#include <hip/hip_runtime.h>
#include <climits>

// out[i] = cond * prod_{e: idx[e]==i} factor[e];  cond = 1 - clip(t0,0,1)
// log(factor) = logC - u,  u = 0.5*((v-t2)/t1)^2,  logC = log(t0c*INV_SQRT_2PI/t1)
//
// R10: bin stage is a 32-slot RING per bucket (XOR-swizzled banks). Flush
// writes whole physical 16-record halves -> the R8/R9 divergent dependent
// remainder-copy chain (~1.4K cy/tile) is gone; carry stays in place.
// TILE 2048->4096 halves barrier count. Spilled positions form a contiguous
// tail (pos >= flushed+32) -> scnt clamped after flush keeps counts exact.
// Reduce unchanged (packed int LDS atomics, readlane counts, region swizzle).

#define INV_SQRT_2PI 0.39894246f  // 1/sqrt(2*3.14159) (matches reference)
#define SLOT_BITS 14
#define SLOTS (1 << SLOT_BITS)
#define NB_MAX 512          // max buckets for fast path
#define NBLK 512            // binning blocks (block-private regions)
#define BTHREADS 512        // bin block threads
#define TILE 4096           // events per block-tile (8 per thread)
#define RING 32             // ring slots per bucket (pow2)
#define QSCALE 8192.0f
#define QMASK 0x3FFFFu      // 18 bits

#define LDS_BAR() do {                                        \
    asm volatile("s_waitcnt lgkmcnt(0)" ::: "memory");        \
    __builtin_amdgcn_s_barrier();                             \
} while (0)

__device__ __forceinline__ long long region_idx(int blk, int b, int nbuckets,
                                                int swzmask) {
    int bb = swzmask ? ((b + blk) & swzmask) : b;
    return (long long)blk * nbuckets + bb;
}

__device__ __forceinline__ int ring_slot(int b, int pos) {
    return b * RING + ((pos & (RING - 1)) ^ ((b & 7) << 2));
}

__device__ __forceinline__ void ovf_push(uint2* ovf, int* ovf_cnt, int ovcap,
                                         unsigned gslot, unsigned q) {
    int op = atomicAdd(ovf_cnt, 1);
    if (op < ovcap) ovf[op] = make_uint2(gslot, q);
}

__global__ __launch_bounds__(BTHREADS) void bin_kernel(
        const int* __restrict__ idx, const float* __restrict__ vals,
        const float* __restrict__ thetas,
        unsigned* __restrict__ pairs,  // [NBLK][nbuckets][cappb] (swizzled)
        int* __restrict__ fill,        // [NBLK][nbuckets] valid counts (swizzled)
        uint2* __restrict__ ovf, int* __restrict__ ovf_cnt, int ovcap,
        int n, int nbuckets, int cap_shift, int swzmask, int epb) {
    __shared__ unsigned ring[NB_MAX * RING];   // 64 KB
    __shared__ int scnt[NB_MAX];               // total records (logical end)
    __shared__ int cnum[NB_MAX];               // 16-rec chunks flushed

    const int tid = threadIdx.x;
    const int blk = blockIdx.x;
    const int cappb = 1 << cap_shift;
    long long start = (long long)blk * epb;
    long long end = start + epb;
    if (end > n) end = n;

    for (int b = tid; b < nbuckets; b += BTHREADS) { scnt[b] = 0; cnum[b] = 0; }
    __syncthreads();

    const float t1 = thetas[1], t2 = thetas[2];
    const float t0c = fminf(fmaxf(thetas[0], 0.0f), 1.0f);
    const float inv_t1 = 1.0f / t1;

    // prefetch tile 0 (8 events/thread)
    int   kk[8]; float vv[8]; int cnt_ev = 0;
    int   nk[8]; float nv[8];
    {
        long long te0 = start + TILE; if (te0 > end) te0 = end;
        long long base = start + (long long)tid * 8;
        if (base + 8 <= te0) {
            int4 k0 = *(const int4*)(idx + base);
            int4 k1 = *(const int4*)(idx + base + 4);
            float4 v0 = *(const float4*)(vals + base);
            float4 v1 = *(const float4*)(vals + base + 4);
            kk[0]=k0.x;kk[1]=k0.y;kk[2]=k0.z;kk[3]=k0.w;
            kk[4]=k1.x;kk[5]=k1.y;kk[6]=k1.z;kk[7]=k1.w;
            vv[0]=v0.x;vv[1]=v0.y;vv[2]=v0.z;vv[3]=v0.w;
            vv[4]=v1.x;vv[5]=v1.y;vv[6]=v1.z;vv[7]=v1.w;
            cnt_ev = 8;
        } else if (base < te0) {
            cnt_ev = (int)(te0 - base);
            #pragma unroll
            for (int i = 0; i < 8; ++i) { kk[i] = 0; vv[i] = 0.0f; }
            for (int i = 0; i < cnt_ev; ++i) { kk[i] = idx[base+i]; vv[i] = vals[base+i]; }
        }
    }

    for (long long ts = start; ts < end; ts += TILE) {
        // ---- prefetch next tile ----
        int nxt_cnt = 0;
        long long tsn = ts + TILE;
        if (tsn < end) {
            long long ten = tsn + TILE; if (ten > end) ten = end;
            long long base = tsn + (long long)tid * 8;
            if (base + 8 <= ten) {
                int4 k0 = *(const int4*)(idx + base);
                int4 k1 = *(const int4*)(idx + base + 4);
                float4 v0 = *(const float4*)(vals + base);
                float4 v1 = *(const float4*)(vals + base + 4);
                nk[0]=k0.x;nk[1]=k0.y;nk[2]=k0.z;nk[3]=k0.w;
                nk[4]=k1.x;nk[5]=k1.y;nk[6]=k1.z;nk[7]=k1.w;
                nv[0]=v0.x;nv[1]=v0.y;nv[2]=v0.z;nv[3]=v0.w;
                nv[4]=v1.x;nv[5]=v1.y;nv[6]=v1.z;nv[7]=v1.w;
                nxt_cnt = 8;
            } else if (base < ten) {
                nxt_cnt = (int)(ten - base);
                #pragma unroll
                for (int i = 0; i < 8; ++i) { nk[i] = 0; nv[i] = 0.0f; }
                for (int i = 0; i < nxt_cnt; ++i) { nk[i] = idx[base+i]; nv[i] = vals[base+i]; }
            }
        }

        // ---- phase 1: compute records ----
        int bs[8]; unsigned recs[8]; int pos[8]; int win[8];
        #pragma unroll
        for (int j = 0; j < 8; ++j) {
            unsigned uk = (unsigned)kk[j];
            bs[j] = (int)(uk >> SLOT_BITS);
            float z = (vv[j] - t2) * inv_t1;
            float u = 0.5f * z * z;
            unsigned q = __float2uint_rn(fminf(u * QSCALE, (float)QMASK));
            recs[j] = ((uk & (SLOTS - 1)) << 18) | q;
        }
        // ---- phase 2: window bases (cnum stable this phase) + atomics ----
        #pragma unroll
        for (int j = 0; j < 8; ++j) {
            bool ok = (j < cnt_ev) && (bs[j] < nbuckets);
            win[j] = ok ? (cnum[bs[j]] << 4) : 0;
            pos[j] = ok ? atomicAdd(&scnt[bs[j]], 1) : INT_MAX;
        }
        // ---- phase 3: ring stores (or rare tail spill) ----
        #pragma unroll
        for (int j = 0; j < 8; ++j) {
            if (pos[j] == INT_MAX) continue;
            if (pos[j] - win[j] < RING)
                ring[ring_slot(bs[j], pos[j])] = recs[j];
            else
                ovf_push(ovf, ovf_cnt, ovcap, (unsigned)kk[j], recs[j] & QMASK);
        }
        LDS_BAR();

        // ---- flush: whole physical halves, no data movement in LDS ----
        for (int b = tid; b < nbuckets; b += BTHREADS) {
            int c = scnt[b];
            int J = cnum[b];
            int flushed = J << 4;
            int stored_end = c < flushed + RING ? c : flushed + RING;
            int navail = stored_end - flushed;
            while (navail >= 16) {
                int H = (J & 1) ^ ((b >> 2) & 1);   // physical half of ring
                const uint4* s4 = (const uint4*)&ring[b * RING + (H << 4)];
                if (J < (cappb >> 4)) {
                    uint4* d4 = (uint4*)(pairs +
                        (region_idx(blk, b, nbuckets, swzmask) << cap_shift) + (J << 4));
                    d4[0]=s4[0]; d4[1]=s4[1]; d4[2]=s4[2]; d4[3]=s4[3];
                } else {  // region full (practically never)
                    for (int i = 0; i < 16; ++i) {
                        unsigned r = ring[b * RING + (H << 4) + i];
                        ovf_push(ovf, ovf_cnt, ovcap,
                                 ((unsigned)b << SLOT_BITS) | (r >> 18), r & QMASK);
                    }
                }
                ++J; flushed += 16; navail -= 16;
            }
            cnum[b] = J;
            if (c != stored_end) scnt[b] = stored_end;  // drop spilled tail
        }
        LDS_BAR();

        cnt_ev = nxt_cnt;
        #pragma unroll
        for (int j = 0; j < 8; ++j) { kk[j] = nk[j]; vv[j] = nv[j]; }
    }

    // ---- final flush: partial chunk in LOGICAL order (un-permuted) ----
    for (int b = tid; b < nbuckets; b += BTHREADS) {
        int c = scnt[b];
        int J = cnum[b];
        int flushed = J << 4;
        int r = c - flushed;                 // 0..15
        int valid = flushed;
        if (r > 0 && J < (cappb >> 4)) {
            unsigned tmp[16];
            int lbase = (J & 1) << 4;        // logical half base (flushed%32)
            #pragma unroll
            for (int i = 0; i < 16; ++i)
                tmp[i] = ring[b * RING + ((lbase + i) ^ ((b & 7) << 2))];
            uint4* d4 = (uint4*)(pairs +
                (region_idx(blk, b, nbuckets, swzmask) << cap_shift) + (J << 4));
            const uint4* t4 = (const uint4*)tmp;
            d4[0]=t4[0]; d4[1]=t4[1]; d4[2]=t4[2]; d4[3]=t4[3];
            valid = flushed + r;
        } else if (r > 0) {                  // region full: spill tail
            int lbase = (J & 1) << 4;
            for (int i = 0; i < r; ++i) {
                unsigned rr = ring[b * RING + ((lbase + i) ^ ((b & 7) << 2))];
                ovf_push(ovf, ovf_cnt, ovcap,
                         ((unsigned)b << SLOT_BITS) | (rr >> 18), rr & QMASK);
            }
        }
        fill[region_idx(blk, b, nbuckets, swzmask)] = valid;
    }
}

__global__ __launch_bounds__(1024) void reduce_kernel(
        const unsigned* __restrict__ pairs, const int* __restrict__ fill,
        const uint2* __restrict__ ovf, const int* __restrict__ ovf_cnt, int ovcap,
        const float* __restrict__ thetas, float* __restrict__ out,
        long long n_out, int nbuckets, int cap_shift, int swzmask) {
    __shared__ unsigned accu[SLOTS];   // 64 KB packed: count<<25 | sum_q
    const int tid = threadIdx.x;
    const int b = blockIdx.x;

    for (int s = tid; s < SLOTS; s += 1024) accu[s] = 0u;
    __syncthreads();

    const int wave = tid >> 6, lane = tid & 63;
    const int SEGS = NBLK / 16;   // 32 segments per wave

    // preload this wave's segment counts: lane i holds cnt(seg wave+i*16)
    int sl = wave + (lane & 31) * 16;
    int cntv = fill[region_idx(sl, b, nbuckets, swzmask)];

    // pipelined segment stream: records read unconditionally (2x256B/seg)
    const unsigned* pc = pairs +
        (region_idx(wave, b, nbuckets, swzmask) << cap_shift);
    unsigned a0 = pc[lane];
    unsigned a1 = pc[64 + lane];

    for (int i = 0; i < SEGS; ++i) {
        const unsigned* pn = pc; unsigned n0 = 0, n1 = 0;
        if (i < SEGS - 1) {
            int sn = wave + (i + 1) * 16;
            pn = pairs + (region_idx(sn, b, nbuckets, swzmask) << cap_shift);
            n0 = pn[lane];
            n1 = pn[64 + lane];
        }
        int ca = __builtin_amdgcn_readlane(cntv, i);
        if (lane < ca)      atomicAdd(&accu[a0 >> 18], (1u << 25) + (a0 & QMASK));
        if (64 + lane < ca) atomicAdd(&accu[a1 >> 18], (1u << 25) + (a1 & QMASK));
        for (int r = 128 + lane; r < ca; r += 64) {   // only if cap_shift > 7
            unsigned rec = pc[r];
            atomicAdd(&accu[rec >> 18], (1u << 25) + (rec & QMASK));
        }
        pc = pn; a0 = n0; a1 = n1;
    }
    __syncthreads();

    int no = *ovf_cnt; if (no > ovcap) no = ovcap;
    for (int i = tid; i < no; i += 1024) {
        uint2 e = ovf[i];
        if ((int)(e.x >> SLOT_BITS) == b)
            atomicAdd(&accu[e.x & (SLOTS - 1)], (1u << 25) + e.y);
    }
    __syncthreads();

    const float t1 = thetas[1];
    const float t0c = fminf(fmaxf(thetas[0], 0.0f), 1.0f);
    const float logC = logf(t0c * INV_SQRT_2PI / t1);
    const float cond = 1.0f - t0c;
    long long obase = (long long)b << SLOT_BITS;
    for (int ss = tid; ss < SLOTS; ss += 1024) {
        long long o = obase + ss;
        if (o < n_out) {
            unsigned av = accu[ss];
            float v = (float)(av >> 25) * logC
                    - (float)(av & 0x1FFFFFFu) * (1.0f / QSCALE);
            out[o] = cond * expf(v);
        }
    }
}

// ---- fallback path: direct global atomics (R1) ----
__global__ void init_zero_kernel(float* __restrict__ out, int n) {
    int i = blockIdx.x * blockDim.x + threadIdx.x;
    int stride = gridDim.x * blockDim.x;
    for (; i < n; i += stride) out[i] = 0.0f;
}
__global__ void scatter_log_kernel(const int* __restrict__ idx,
                                   const float* __restrict__ vals,
                                   const float* __restrict__ thetas,
                                   float* __restrict__ acc, int n) {
    float t1 = thetas[1], t2 = thetas[2];
    float t0c = fminf(fmaxf(thetas[0], 0.0f), 1.0f);
    float logC = logf(t0c * INV_SQRT_2PI / t1);
    float inv_t1 = 1.0f / t1;
    int i = blockIdx.x * blockDim.x + threadIdx.x;
    int stride = gridDim.x * blockDim.x;
    for (; i < n; i += stride) {
        float z = (vals[i] - t2) * inv_t1;
        atomicAdd(&acc[idx[i]], fmaf(-0.5f * z, z, logC));
    }
}
__global__ void finalize_kernel(float* __restrict__ out,
                                const float* __restrict__ thetas, int n) {
    float t0c = fminf(fmaxf(thetas[0], 0.0f), 1.0f);
    float cond = 1.0f - t0c;
    int i = blockIdx.x * blockDim.x + threadIdx.x;
    int stride = gridDim.x * blockDim.x;
    for (; i < n; i += stride) out[i] = cond * expf(out[i]);
}

extern "C" void kernel_launch(void* const* d_in, const int* in_sizes, int n_in,
                              void* d_out, int out_size, void* d_ws, size_t ws_size,
                              hipStream_t stream) {
    // inputs: [0]=batch (scalar), [1]=idx (int32), [2]=vals (f32), [3]=thetas (f32 x3)
    const int*   idx    = (const int*)d_in[1];
    const float* vals   = (const float*)d_in[2];
    const float* thetas = (const float*)d_in[3];
    float*       out    = (float*)d_out;

    int n_events = in_sizes[1];
    long long n_out = out_size;
    int nbuckets = (int)((n_out + SLOTS - 1) >> SLOT_BITS);

    // geometry
    long long tiles_total = ((long long)n_events + TILE - 1) / TILE;
    long long tpb = (tiles_total + NBLK - 1) / NBLK;
    int epb = (int)(tpb * TILE);
    long long avg = nbuckets > 0 ? (epb + nbuckets - 1) / nbuckets : 1;
    long long want = avg + avg / 2 + 32;        // Poisson mean avg, >>6 sigma
    int cap_shift = 6;
    while ((1LL << cap_shift) < want && cap_shift < 20) ++cap_shift;
    long long cappb = 1LL << cap_shift;
    int swzmask = (nbuckets > 0 && (nbuckets & (nbuckets - 1)) == 0)
                  ? nbuckets - 1 : 0;

    size_t pairs_b = (size_t)NBLK * nbuckets * cappb * 4;
    size_t fill_b  = (size_t)NBLK * nbuckets * 4;
    size_t head    = pairs_b + fill_b + 64;
    bool fast = (nbuckets > 0) && (nbuckets <= NB_MAX) && (n_events > 0) &&
                (ws_size >= head + 64 * 1024);

    if (fast) {
        unsigned* pairs = (unsigned*)d_ws;
        int* fill = (int*)((char*)d_ws + pairs_b);
        int* ovf_cnt = (int*)((char*)d_ws + pairs_b + fill_b);
        uint2* ovf = (uint2*)((char*)d_ws + head);
        long long ovcap_ll = (long long)((ws_size - head) / 8);
        int ovcap = (int)(ovcap_ll > 4194304 ? 4194304 : ovcap_ll);

        hipMemsetAsync(ovf_cnt, 0, sizeof(int), stream);
        bin_kernel<<<NBLK, BTHREADS, 0, stream>>>(idx, vals, thetas, pairs, fill,
                                                  ovf, ovf_cnt, ovcap,
                                                  n_events, nbuckets, cap_shift,
                                                  swzmask, epb);
        reduce_kernel<<<nbuckets, 1024, 0, stream>>>(pairs, fill, ovf, ovf_cnt,
                                                     ovcap, thetas, out,
                                                     n_out, nbuckets, cap_shift,
                                                     swzmask);
    } else {
        const int BLOCK = 256;
        int grid_out = min((int)((n_out + BLOCK - 1) / BLOCK), 2048);
        int grid_ev  = min((n_events + BLOCK - 1) / BLOCK, 2048);
        init_zero_kernel<<<grid_out, BLOCK, 0, stream>>>(out, (int)n_out);
        scatter_log_kernel<<<grid_ev, BLOCK, 0, stream>>>(idx, vals, thetas, out, n_events);
        finalize_kernel<<<grid_out, BLOCK, 0, stream>>>(out, thetas, (int)n_out);
    }
}

// Round 11
// 96.425 us; speedup vs baseline: 8.5615x; 1.0213x over previous
//
#include <hip/hip_runtime.h>
#include <climits>

// out[i] = cond * prod_{e: idx[e]==i} factor[e];  cond = 1 - clip(t0,0,1)
// log(factor) = logC - u,  u = 0.5*((v-t2)/t1)^2,  logC = log(t0c*INV_SQRT_2PI/t1)
//
// R11: bin at 1024 threads (32 waves/CU), flush window packed into scnt's
// upper bits ((J<<20)|count -> ONE atomic returns pos AND window; 2 DS ops
// per event), slot-major ring [32][nb] (flush reads are bank-b%32 scalar
// b32 -> 2-way aliasing only; no XOR swizzle; final flush in logical order).
// Reduce unchanged (packed int LDS atomics, readlane counts, region swizzle).

#define INV_SQRT_2PI 0.39894246f  // 1/sqrt(2*3.14159) (matches reference)
#define SLOT_BITS 14
#define SLOTS (1 << SLOT_BITS)
#define NB_MAX 512          // max buckets for fast path
#define NBLK 512            // binning blocks (block-private regions)
#define BTHREADS 1024       // bin block threads
#define TILE 4096           // events per block-tile (4 per thread)
#define RING 32             // ring slots per bucket (pow2, one 16-rec chunk x2)
#define QSCALE 8192.0f
#define QMASK 0x3FFFFu      // 18 bits
#define CMASK 0xFFFFFu      // low 20 bits of scnt = record count

#define LDS_BAR() do {                                        \
    asm volatile("s_waitcnt lgkmcnt(0)" ::: "memory");        \
    __builtin_amdgcn_s_barrier();                             \
} while (0)

__device__ __forceinline__ long long region_idx(int blk, int b, int nbuckets,
                                                int swzmask) {
    int bb = swzmask ? ((b + blk) & swzmask) : b;
    return (long long)blk * nbuckets + bb;
}

__device__ __forceinline__ void ovf_push(uint2* ovf, int* ovf_cnt, int ovcap,
                                         unsigned gslot, unsigned q) {
    int op = atomicAdd(ovf_cnt, 1);
    if (op < ovcap) ovf[op] = make_uint2(gslot, q);
}

__global__ __launch_bounds__(BTHREADS) void bin_kernel(
        const int* __restrict__ idx, const float* __restrict__ vals,
        const float* __restrict__ thetas,
        unsigned* __restrict__ pairs,  // [NBLK][nbuckets][cappb] (swizzled)
        int* __restrict__ fill,        // [NBLK][nbuckets] valid counts (swizzled)
        uint2* __restrict__ ovf, int* __restrict__ ovf_cnt, int ovcap,
        int n, int nbuckets, int cap_shift, int swzmask, int epb) {
    __shared__ unsigned ring[RING * NB_MAX];   // slot-major [32][nb], 64 KB
    __shared__ int scnt[NB_MAX];               // packed (chunks<<20)|count

    const int tid = threadIdx.x;
    const int blk = blockIdx.x;
    const int cappb = 1 << cap_shift;
    long long start = (long long)blk * epb;
    long long end = start + epb;
    if (end > n) end = n;

    for (int b = tid; b < nbuckets; b += BTHREADS) scnt[b] = 0;
    __syncthreads();

    const float t1 = thetas[1], t2 = thetas[2];
    const float t0c = fminf(fmaxf(thetas[0], 0.0f), 1.0f);
    const float inv_t1 = 1.0f / t1;

    // prefetch tile 0 (4 events/thread: one int4 + one float4)
    int4 ck = make_int4(0,0,0,0); float4 cv = make_float4(0,0,0,0); int ccnt = 0;
    int4 pk_; float4 pv_;
    {
        long long te0 = start + TILE; if (te0 > end) te0 = end;
        long long base = start + (long long)tid * 4;
        if (base + 4 <= te0) {
            ck = *(const int4*)(idx + base);
            cv = *(const float4*)(vals + base);
            ccnt = 4;
        } else if (base < te0) {
            ccnt = (int)(te0 - base);
            int kk[4] = {0,0,0,0}; float vv[4] = {0,0,0,0};
            for (int i = 0; i < ccnt; ++i) { kk[i]=idx[base+i]; vv[i]=vals[base+i]; }
            ck = make_int4(kk[0],kk[1],kk[2],kk[3]);
            cv = make_float4(vv[0],vv[1],vv[2],vv[3]);
        }
    }

    for (long long ts = start; ts < end; ts += TILE) {
        // ---- prefetch next tile ----
        int ncnt = 0;
        long long tsn = ts + TILE;
        if (tsn < end) {
            long long ten = tsn + TILE; if (ten > end) ten = end;
            long long base = tsn + (long long)tid * 4;
            if (base + 4 <= ten) {
                pk_ = *(const int4*)(idx + base);
                pv_ = *(const float4*)(vals + base);
                ncnt = 4;
            } else if (base < ten) {
                ncnt = (int)(ten - base);
                int kk[4] = {0,0,0,0}; float vv[4] = {0,0,0,0};
                for (int i = 0; i < ncnt; ++i) { kk[i]=idx[base+i]; vv[i]=vals[base+i]; }
                pk_ = make_int4(kk[0],kk[1],kk[2],kk[3]);
                pv_ = make_float4(vv[0],vv[1],vv[2],vv[3]);
            }
        }

        // ---- compute records ----
        int   kk[4] = {ck.x, ck.y, ck.z, ck.w};
        float vv[4] = {cv.x, cv.y, cv.z, cv.w};
        int bs[4]; unsigned recs[4];
        #pragma unroll
        for (int j = 0; j < 4; ++j) {
            unsigned uk = (unsigned)kk[j];
            bs[j] = (int)(uk >> SLOT_BITS);
            float z = (vv[j] - t2) * inv_t1;
            float u = 0.5f * z * z;
            unsigned q = __float2uint_rn(fminf(u * QSCALE, (float)QMASK));
            recs[j] = ((uk & (SLOTS - 1)) << 18) | q;
        }
        // ---- one atomic per event returns pos AND flush window ----
        int ret[4];
        #pragma unroll
        for (int j = 0; j < 4; ++j) {
            ret[j] = (j < ccnt && bs[j] < nbuckets)
                     ? atomicAdd(&scnt[bs[j]], 1) : INT_MIN;
        }
        #pragma unroll
        for (int j = 0; j < 4; ++j) {
            if (ret[j] == INT_MIN) continue;
            int pos = ret[j] & CMASK;
            int fl  = (ret[j] >> 20) << 4;     // chunks flushed * 16
            if (pos - fl < RING)
                ring[(pos & (RING - 1)) * nbuckets + bs[j]] = recs[j];
            else
                ovf_push(ovf, ovf_cnt, ovcap, (unsigned)kk[j], recs[j] & QMASK);
        }
        LDS_BAR();

        // ---- flush whole 16-record halves (conflict-free b%32 reads) ----
        for (int b = tid; b < nbuckets; b += BTHREADS) {
            int pk = scnt[b];
            int c = pk & CMASK;
            int J = pk >> 20;
            int fl = J << 4;
            int se = c < fl + RING ? c : fl + RING;   // clamp spilled tail
            int na = se - fl;
            int J0 = J;
            while (na >= 16) {
                int H = (J & 1) << 4;                 // physical half base slot
                unsigned tmp[16];
                #pragma unroll
                for (int i = 0; i < 16; ++i)
                    tmp[i] = ring[(H + i) * nbuckets + b];
                if (J < (cappb >> 4)) {
                    uint4* d4 = (uint4*)(pairs +
                        (region_idx(blk, b, nbuckets, swzmask) << cap_shift) + (J << 4));
                    const uint4* t4 = (const uint4*)tmp;
                    d4[0]=t4[0]; d4[1]=t4[1]; d4[2]=t4[2]; d4[3]=t4[3];
                } else {  // region full (practically never)
                    for (int i = 0; i < 16; ++i) {
                        unsigned r = tmp[i];
                        ovf_push(ovf, ovf_cnt, ovcap,
                                 ((unsigned)b << SLOT_BITS) | (r >> 18), r & QMASK);
                    }
                }
                ++J; fl += 16; na -= 16;
            }
            if (J != J0 || se != c) scnt[b] = (J << 20) | se;
        }
        LDS_BAR();

        ck = pk_; cv = pv_; ccnt = ncnt;
    }

    // ---- final flush: partial chunk (logical order = slot order) ----
    for (int b = tid; b < nbuckets; b += BTHREADS) {
        int pk = scnt[b];
        int c = pk & CMASK;
        int J = pk >> 20;
        int fl = J << 4;
        int r = c - fl;                      // 0..15
        int valid = fl;
        if (r > 0 && J < (cappb >> 4)) {
            int H = (J & 1) << 4;
            unsigned tmp[16];
            #pragma unroll
            for (int i = 0; i < 16; ++i)
                tmp[i] = ring[(H + i) * nbuckets + b];
            uint4* d4 = (uint4*)(pairs +
                (region_idx(blk, b, nbuckets, swzmask) << cap_shift) + (J << 4));
            const uint4* t4 = (const uint4*)tmp;
            d4[0]=t4[0]; d4[1]=t4[1]; d4[2]=t4[2]; d4[3]=t4[3];
            valid = fl + r;
        } else if (r > 0) {
            int H = (J & 1) << 4;
            for (int i = 0; i < r; ++i) {
                unsigned rr = ring[(H + i) * nbuckets + b];
                ovf_push(ovf, ovf_cnt, ovcap,
                         ((unsigned)b << SLOT_BITS) | (rr >> 18), rr & QMASK);
            }
        }
        fill[region_idx(blk, b, nbuckets, swzmask)] = valid;
    }
}

__global__ __launch_bounds__(1024) void reduce_kernel(
        const unsigned* __restrict__ pairs, const int* __restrict__ fill,
        const uint2* __restrict__ ovf, const int* __restrict__ ovf_cnt, int ovcap,
        const float* __restrict__ thetas, float* __restrict__ out,
        long long n_out, int nbuckets, int cap_shift, int swzmask) {
    __shared__ unsigned accu[SLOTS];   // 64 KB packed: count<<25 | sum_q
    const int tid = threadIdx.x;
    const int b = blockIdx.x;

    for (int s = tid; s < SLOTS; s += 1024) accu[s] = 0u;
    __syncthreads();

    const int wave = tid >> 6, lane = tid & 63;
    const int SEGS = NBLK / 16;   // 32 segments per wave

    // preload this wave's segment counts: lane i holds cnt(seg wave+i*16)
    int sl = wave + (lane & 31) * 16;
    int cntv = fill[region_idx(sl, b, nbuckets, swzmask)];

    // pipelined segment stream: records read unconditionally (2x256B/seg)
    const unsigned* pc = pairs +
        (region_idx(wave, b, nbuckets, swzmask) << cap_shift);
    unsigned a0 = pc[lane];
    unsigned a1 = pc[64 + lane];

    for (int i = 0; i < SEGS; ++i) {
        const unsigned* pn = pc; unsigned n0 = 0, n1 = 0;
        if (i < SEGS - 1) {
            int sn = wave + (i + 1) * 16;
            pn = pairs + (region_idx(sn, b, nbuckets, swzmask) << cap_shift);
            n0 = pn[lane];
            n1 = pn[64 + lane];
        }
        int ca = __builtin_amdgcn_readlane(cntv, i);
        if (lane < ca)      atomicAdd(&accu[a0 >> 18], (1u << 25) + (a0 & QMASK));
        if (64 + lane < ca) atomicAdd(&accu[a1 >> 18], (1u << 25) + (a1 & QMASK));
        for (int r = 128 + lane; r < ca; r += 64) {   // only if cap_shift > 7
            unsigned rec = pc[r];
            atomicAdd(&accu[rec >> 18], (1u << 25) + (rec & QMASK));
        }
        pc = pn; a0 = n0; a1 = n1;
    }
    __syncthreads();

    int no = *ovf_cnt; if (no > ovcap) no = ovcap;
    for (int i = tid; i < no; i += 1024) {
        uint2 e = ovf[i];
        if ((int)(e.x >> SLOT_BITS) == b)
            atomicAdd(&accu[e.x & (SLOTS - 1)], (1u << 25) + e.y);
    }
    __syncthreads();

    const float t1 = thetas[1];
    const float t0c = fminf(fmaxf(thetas[0], 0.0f), 1.0f);
    const float logC = logf(t0c * INV_SQRT_2PI / t1);
    const float cond = 1.0f - t0c;
    long long obase = (long long)b << SLOT_BITS;
    for (int ss = tid; ss < SLOTS; ss += 1024) {
        long long o = obase + ss;
        if (o < n_out) {
            unsigned av = accu[ss];
            float v = (float)(av >> 25) * logC
                    - (float)(av & 0x1FFFFFFu) * (1.0f / QSCALE);
            out[o] = cond * expf(v);
        }
    }
}

// ---- fallback path: direct global atomics (R1) ----
__global__ void init_zero_kernel(float* __restrict__ out, int n) {
    int i = blockIdx.x * blockDim.x + threadIdx.x;
    int stride = gridDim.x * blockDim.x;
    for (; i < n; i += stride) out[i] = 0.0f;
}
__global__ void scatter_log_kernel(const int* __restrict__ idx,
                                   const float* __restrict__ vals,
                                   const float* __restrict__ thetas,
                                   float* __restrict__ acc, int n) {
    float t1 = thetas[1], t2 = thetas[2];
    float t0c = fminf(fmaxf(thetas[0], 0.0f), 1.0f);
    float logC = logf(t0c * INV_SQRT_2PI / t1);
    float inv_t1 = 1.0f / t1;
    int i = blockIdx.x * blockDim.x + threadIdx.x;
    int stride = gridDim.x * blockDim.x;
    for (; i < n; i += stride) {
        float z = (vals[i] - t2) * inv_t1;
        atomicAdd(&acc[idx[i]], fmaf(-0.5f * z, z, logC));
    }
}
__global__ void finalize_kernel(float* __restrict__ out,
                                const float* __restrict__ thetas, int n) {
    float t0c = fminf(fmaxf(thetas[0], 0.0f), 1.0f);
    float cond = 1.0f - t0c;
    int i = blockIdx.x * blockDim.x + threadIdx.x;
    int stride = gridDim.x * blockDim.x;
    for (; i < n; i += stride) out[i] = cond * expf(out[i]);
}

extern "C" void kernel_launch(void* const* d_in, const int* in_sizes, int n_in,
                              void* d_out, int out_size, void* d_ws, size_t ws_size,
                              hipStream_t stream) {
    // inputs: [0]=batch (scalar), [1]=idx (int32), [2]=vals (f32), [3]=thetas (f32 x3)
    const int*   idx    = (const int*)d_in[1];
    const float* vals   = (const float*)d_in[2];
    const float* thetas = (const float*)d_in[3];
    float*       out    = (float*)d_out;

    int n_events = in_sizes[1];
    long long n_out = out_size;
    int nbuckets = (int)((n_out + SLOTS - 1) >> SLOT_BITS);

    // geometry
    long long tiles_total = ((long long)n_events + TILE - 1) / TILE;
    long long tpb = (tiles_total + NBLK - 1) / NBLK;
    int epb = (int)(tpb * TILE);
    long long avg = nbuckets > 0 ? (epb + nbuckets - 1) / nbuckets : 1;
    long long want = avg + avg / 2 + 32;        // Poisson mean avg, >>6 sigma
    int cap_shift = 6;
    while ((1LL << cap_shift) < want && cap_shift < 20) ++cap_shift;
    long long cappb = 1LL << cap_shift;
    int swzmask = (nbuckets > 0 && (nbuckets & (nbuckets - 1)) == 0)
                  ? nbuckets - 1 : 0;

    size_t pairs_b = (size_t)NBLK * nbuckets * cappb * 4;
    size_t fill_b  = (size_t)NBLK * nbuckets * 4;
    size_t head    = pairs_b + fill_b + 64;
    bool fast = (nbuckets > 0) && (nbuckets <= NB_MAX) && (n_events > 0) &&
                (ws_size >= head + 64 * 1024) &&
                ((long long)NBLK * 2048 /*epb cap*/ , true);

    if (fast) {
        unsigned* pairs = (unsigned*)d_ws;
        int* fill = (int*)((char*)d_ws + pairs_b);
        int* ovf_cnt = (int*)((char*)d_ws + pairs_b + fill_b);
        uint2* ovf = (uint2*)((char*)d_ws + head);
        long long ovcap_ll = (long long)((ws_size - head) / 8);
        int ovcap = (int)(ovcap_ll > 4194304 ? 4194304 : ovcap_ll);

        hipMemsetAsync(ovf_cnt, 0, sizeof(int), stream);
        bin_kernel<<<NBLK, BTHREADS, 0, stream>>>(idx, vals, thetas, pairs, fill,
                                                  ovf, ovf_cnt, ovcap,
                                                  n_events, nbuckets, cap_shift,
                                                  swzmask, epb);
        reduce_kernel<<<nbuckets, 1024, 0, stream>>>(pairs, fill, ovf, ovf_cnt,
                                                     ovcap, thetas, out,
                                                     n_out, nbuckets, cap_shift,
                                                     swzmask);
    } else {
        const int BLOCK = 256;
        int grid_out = min((int)((n_out + BLOCK - 1) / BLOCK), 2048);
        int grid_ev  = min((n_events + BLOCK - 1) / BLOCK, 2048);
        init_zero_kernel<<<grid_out, BLOCK, 0, stream>>>(out, (int)n_out);
        scatter_log_kernel<<<grid_ev, BLOCK, 0, stream>>>(idx, vals, thetas, out, n_events);
        finalize_kernel<<<grid_out, BLOCK, 0, stream>>>(out, thetas, (int)n_out);
    }
}